// Round 1
// baseline (502.522 us; speedup 1.0000x reference)
//
#include <hip/hip_runtime.h>

#define NN 10000
#define CC 128
#define HH 256
#define EE 320000

typedef __bf16 bf16_t;
typedef __bf16 bf16x8 __attribute__((ext_vector_type(8)));
typedef float f32x4 __attribute__((ext_vector_type(4)));

__device__ __forceinline__ float silu_f(float v) {
  return v / (1.0f + __expf(-v));
}

// Wave-level 64xN GEMM slab: A (64 x KD bf16) in LDS (row stride SA, padded to
// break bank aliasing), B^T (Ncols x KD bf16) streamed from global (L2-hot).
// Each wave computes 64 rows x (16*NT) cols starting at col nwavebase.
// Fragment layouts per guide §3 (m89/m120-verified):
//   A: lane holds A[m=lane&15][k=quad*8+j]; B: B[k=quad*8+j][n=lane&15]
//   C/D: col=lane&15, row=quad*4+reg
template<int KD, int SA, int NT>
__device__ __forceinline__ void gemm_block(const bf16_t* sAa, const bf16_t* __restrict__ BT,
                                           int nwavebase, int lr, int quad, f32x4 acc[4][NT]) {
  for (int kk = 0; kk < KD; kk += 32) {
    bf16x8 a[4]; bf16x8 b[NT];
#pragma unroll
    for (int re = 0; re < 4; re++)
      a[re] = *(const bf16x8*)(sAa + (re * 16 + lr) * SA + kk + quad * 8);
#pragma unroll
    for (int ce = 0; ce < NT; ce++)
      b[ce] = *(const bf16x8*)(BT + (size_t)(nwavebase + ce * 16 + lr) * KD + kk + quad * 8);
#pragma unroll
    for (int re = 0; re < 4; re++)
#pragma unroll
      for (int ce = 0; ce < NT; ce++)
        acc[re][ce] = __builtin_amdgcn_mfma_f32_16x16x32_bf16(a[re], b[ce], acc[re][ce], 0, 0, 0);
  }
}

// ---------- weight prep: f32 row-major (K x Nc) -> bf16 transposed (Nc x K) ----------
__global__ __launch_bounds__(256) void transpose_kernel(const float* __restrict__ src,
                                                        bf16_t* __restrict__ dst,
                                                        int K, int Nc) {
  int i = blockIdx.x * 256 + threadIdx.x;
  if (i < K * Nc) {
    int n = i / K;
    int k = i - n * K;
    dst[i] = (bf16_t)src[(size_t)k * Nc + n];
  }
}

// ---------- LayerNorm over 128 channels; optional f32 output ----------
__global__ __launch_bounds__(64) void ln_kernel(const float* __restrict__ src,
                                                const float* __restrict__ g,
                                                const float* __restrict__ b,
                                                float* __restrict__ outf,
                                                bf16_t* __restrict__ out16) {
  int node = blockIdx.x;
  int lane = threadIdx.x;
  size_t base = (size_t)node * CC;
  float v1 = src[base + lane], v2 = src[base + lane + 64];
  float s = v1 + v2, sq = v1 * v1 + v2 * v2;
#pragma unroll
  for (int o = 32; o > 0; o >>= 1) { s += __shfl_xor(s, o); sq += __shfl_xor(sq, o); }
  float mu = s * (1.0f / CC);
  float var = sq * (1.0f / CC) - mu * mu;
  float rs = rsqrtf(var + 1e-5f);
  float a1 = (v1 - mu) * rs * g[lane] + b[lane];
  float a2 = (v2 - mu) * rs * g[lane + 64] + b[lane + 64];
  if (outf) { outf[base + lane] = a1; outf[base + lane + 64] = a2; }
  out16[base + lane] = (bf16_t)a1;
  out16[base + lane + 64] = (bf16_t)a2;
}

// ---------- CSR build: count, exclusive scan, scatter ----------
__global__ __launch_bounds__(256) void count_kernel(const int* __restrict__ ei, int* __restrict__ cnt) {
  int e = blockIdx.x * 256 + threadIdx.x;  // grid covers EE exactly
  atomicAdd(&cnt[ei[EE + e]], 1);
}

__global__ __launch_bounds__(1024) void scan_kernel(const int* __restrict__ cnt, int* __restrict__ cursor) {
  __shared__ int buf[1024];
  int tid = threadIdx.x;
  int base = 0;
  for (int start = 0; start < NN; start += 1024) {
    int i = start + tid;
    int v = (i < NN) ? cnt[i] : 0;
    buf[tid] = v;
    __syncthreads();
    for (int off = 1; off < 1024; off <<= 1) {
      int t = (tid >= off) ? buf[tid - off] : 0;
      __syncthreads();
      buf[tid] += t;
      __syncthreads();
    }
    if (i < NN) cursor[i] = base + buf[tid] - v;  // exclusive
    base += buf[1023];
    __syncthreads();
  }
}

__global__ __launch_bounds__(256) void scatter_kernel(const int* __restrict__ ei,
                                                      int* __restrict__ cursor,
                                                      int* __restrict__ perm) {
  int e = blockIdx.x * 256 + threadIdx.x;
  int c = ei[EE + e];
  int pos = atomicAdd(&cursor[c], 1);
  perm[pos] = e;  // perm holds edge ids grouped by destination (col)
}

// ---------- the heavy one: fused edge MLP + segmented scatter ----------
// 64 CSR-ordered edges per block, 4 waves. One aliased LDS tile (A -> m1 -> m2).
// K=257 folded: dist column handled as rank-1 epilogue add (dist[e]*We1[256,:]).
__global__ __launch_bounds__(256) void edge_mlp_kernel(
    const float* __restrict__ x, const int* __restrict__ ei,
    const bf16_t* __restrict__ hn16, const int* __restrict__ perm,
    const bf16_t* __restrict__ We1T, const float* __restrict__ We1last,
    const float* __restrict__ be1,
    const bf16_t* __restrict__ We2T, const float* __restrict__ be2,
    float* __restrict__ sums) {
  __shared__ __align__(16) bf16_t sA[64 * 264];  // stride 264: +16B pad -> 2-way LDS aliasing (free)
  __shared__ int sRow[64];
  __shared__ int sCol[64];
  __shared__ float sD[64];
  __shared__ float sCc[64];
  int tid = threadIdx.x;
  int lane = tid & 63, wave = tid >> 6;
  int lr = lane & 15, quad = lane >> 4;
  int e0 = blockIdx.x * 64;  // 5000 blocks * 64 = EE exactly

  if (tid < 64) {
    int eid = perm[e0 + tid];
    int r = ei[eid], c = ei[EE + eid];
    float dx = x[3 * r] - x[3 * c];
    float dy = x[3 * r + 1] - x[3 * c + 1];
    float dz = x[3 * r + 2] - x[3 * c + 2];
    float d = sqrtf(dx * dx + dy * dy + dz * dz);
    float cc = (d <= 5.0f) ? 0.5f * (cosf(d * 0.6283185307179586f) + 1.0f) : 0.0f;
    sRow[tid] = r; sCol[tid] = c; sD[tid] = d; sCc[tid] = cc;
  }
  __syncthreads();

  // gather A = [hn[row] | hn[col]] as bf16, 16B chunks
#pragma unroll
  for (int i = 0; i < 8; i++) {
    int o = tid + i * 256;
    int e = o >> 5, q = o & 31;
    int srcrow = (q < 16) ? sRow[e] : sCol[e];
    uint4 v = *(const uint4*)(hn16 + (size_t)srcrow * CC + (q & 15) * 8);
    *(uint4*)(sA + e * 264 + (q & 15) * 8 + ((q < 16) ? 0 : 128)) = v;
  }
  __syncthreads();

  f32x4 zf = {0.f, 0.f, 0.f, 0.f};
  f32x4 acc[4][4];
#pragma unroll
  for (int i = 0; i < 4; i++)
#pragma unroll
    for (int j = 0; j < 4; j++) acc[i][j] = zf;

  gemm_block<256, 264, 4>(sA, We1T, wave * 64, lr, quad, acc);
  __syncthreads();  // all waves done reading A; safe to overwrite with m1

#pragma unroll
  for (int ce = 0; ce < 4; ce++) {
    int n = wave * 64 + ce * 16 + lr;
    float b1 = be1[n];
    float wl = We1last[n];
#pragma unroll
    for (int re = 0; re < 4; re++) {
#pragma unroll
      for (int r = 0; r < 4; r++) {
        int row = re * 16 + quad * 4 + r;
        float v = acc[re][ce][r] + b1 + sD[row] * wl;
        sA[row * 264 + n] = (bf16_t)silu_f(v);
      }
    }
  }
  __syncthreads();

#pragma unroll
  for (int i = 0; i < 4; i++)
#pragma unroll
    for (int j = 0; j < 4; j++) acc[i][j] = zf;

  gemm_block<256, 264, 4>(sA, We2T, wave * 64, lr, quad, acc);
  __syncthreads();  // all waves done reading m1; safe to overwrite with m2

#pragma unroll
  for (int ce = 0; ce < 4; ce++) {
    int n = wave * 64 + ce * 16 + lr;
    float b2 = be2[n];
#pragma unroll
    for (int re = 0; re < 4; re++) {
#pragma unroll
      for (int r = 0; r < 4; r++) {
        int row = re * 16 + quad * 4 + r;
        float v = acc[re][ce][r] + b2;
        sA[row * 264 + n] = (bf16_t)(silu_f(v) * sCc[row]);
      }
    }
  }
  __syncthreads();

  // segmented reduction over CSR-sorted edges: thread tid owns channel tid.
  // sCol is non-decreasing within the tile -> ~2-3 atomic flushes per block.
  float a = 0.0f;
  int cur = sCol[0];
  for (int e = 0; e < 64; e++) {
    int c = sCol[e];
    if (c != cur) {
      atomicAdd(&sums[(size_t)cur * HH + tid], a);
      a = 0.0f;
      cur = c;
    }
    a += (float)sA[e * 264 + tid];
  }
  atomicAdd(&sums[(size_t)cur * HH + tid], a);
}

// ---------- m_aggr = sums / max(cnt,1), to bf16 ----------
__global__ __launch_bounds__(256) void divide_kernel(const float* __restrict__ sums,
                                                     const int* __restrict__ cnt,
                                                     bf16_t* __restrict__ mag16) {
  int i = blockIdx.x * 256 + threadIdx.x;  // grid covers NN*HH exactly; node == blockIdx.x
  float c = fmaxf((float)cnt[i >> 8], 1.0f);
  mag16[i] = (bf16_t)(sums[i] / c);
}

// ---------- node MLP 1: hd = silu([hn|m_aggr]@Wn1+bn1)@Wn2+bn2; h1 = h+hn+hd ----------
__global__ __launch_bounds__(256) void node_mlp1_kernel(
    const float* __restrict__ h, const float* __restrict__ hnf,
    const bf16_t* __restrict__ hn16, const bf16_t* __restrict__ mag16,
    const bf16_t* __restrict__ Wn1T, const float* __restrict__ bn1,
    const bf16_t* __restrict__ Wn2T, const float* __restrict__ bn2,
    float* __restrict__ h1g) {
  __shared__ __align__(16) bf16_t sA[64 * 392];  // K=384 staged, stride 392
  int tid = threadIdx.x;
  int lane = tid & 63, wave = tid >> 6;
  int lr = lane & 15, quad = lane >> 4;
  int n0 = blockIdx.x * 64;

#pragma unroll
  for (int i = 0; i < 12; i++) {
    int o = tid + i * 256;
    int e = o / 48, q = o - e * 48;
    int node = n0 + e;
    uint4 v = {0u, 0u, 0u, 0u};
    if (node < NN) {
      if (q < 16) v = *(const uint4*)(hn16 + (size_t)node * CC + q * 8);
      else        v = *(const uint4*)(mag16 + (size_t)node * HH + (q - 16) * 8);
    }
    *(uint4*)(sA + e * 392 + q * 8) = v;
  }
  __syncthreads();

  f32x4 zf = {0.f, 0.f, 0.f, 0.f};
  f32x4 acc[4][4];
#pragma unroll
  for (int i = 0; i < 4; i++)
#pragma unroll
    for (int j = 0; j < 4; j++) acc[i][j] = zf;

  gemm_block<384, 392, 4>(sA, Wn1T, wave * 64, lr, quad, acc);
  __syncthreads();  // A consumed; reuse sA for hidden activations (stride 264)

#pragma unroll
  for (int ce = 0; ce < 4; ce++) {
    int n = wave * 64 + ce * 16 + lr;
    float b1 = bn1[n];
#pragma unroll
    for (int re = 0; re < 4; re++) {
#pragma unroll
      for (int r = 0; r < 4; r++) {
        int row = re * 16 + quad * 4 + r;
        sA[row * 264 + n] = (bf16_t)silu_f(acc[re][ce][r] + b1);
      }
    }
  }
  __syncthreads();

  f32x4 acc2[4][2];
#pragma unroll
  for (int i = 0; i < 4; i++)
#pragma unroll
    for (int j = 0; j < 2; j++) acc2[i][j] = zf;

  gemm_block<256, 264, 2>(sA, Wn2T, wave * 32, lr, quad, acc2);

#pragma unroll
  for (int ce = 0; ce < 2; ce++) {
    int n = wave * 32 + ce * 16 + lr;
    float b2 = bn2[n];
#pragma unroll
    for (int re = 0; re < 4; re++) {
#pragma unroll
      for (int r = 0; r < 4; r++) {
        int row = re * 16 + quad * 4 + r;
        int node = n0 + row;
        if (node < NN) {
          size_t idx = (size_t)node * CC + n;
          h1g[idx] = h[idx] + hnf[idx] + acc2[re][ce][r] + b2;
        }
      }
    }
  }
}

// ---------- node MLP 2: out = h1 + silu(LN2(h1)@Wm1+bm1)@Wm2+bm2 ----------
__global__ __launch_bounds__(256) void node_mlp2_kernel(
    const bf16_t* __restrict__ h2n16,
    const bf16_t* __restrict__ Wm1T, const float* __restrict__ bm1,
    const bf16_t* __restrict__ Wm2T, const float* __restrict__ bm2,
    const float* __restrict__ h1g, float* __restrict__ out) {
  __shared__ __align__(16) bf16_t sA[64 * 136];
  __shared__ __align__(16) bf16_t sT[64 * 264];
  int tid = threadIdx.x;
  int lane = tid & 63, wave = tid >> 6;
  int lr = lane & 15, quad = lane >> 4;
  int n0 = blockIdx.x * 64;

#pragma unroll
  for (int i = 0; i < 4; i++) {
    int o = tid + i * 256;
    int e = o >> 4, q = o & 15;
    int node = n0 + e;
    uint4 v = {0u, 0u, 0u, 0u};
    if (node < NN) v = *(const uint4*)(h2n16 + (size_t)node * CC + q * 8);
    *(uint4*)(sA + e * 136 + q * 8) = v;
  }
  __syncthreads();

  f32x4 zf = {0.f, 0.f, 0.f, 0.f};
  f32x4 acc[4][4];
#pragma unroll
  for (int i = 0; i < 4; i++)
#pragma unroll
    for (int j = 0; j < 4; j++) acc[i][j] = zf;

  gemm_block<128, 136, 4>(sA, Wm1T, wave * 64, lr, quad, acc);

#pragma unroll
  for (int ce = 0; ce < 4; ce++) {
    int n = wave * 64 + ce * 16 + lr;
    float b1 = bm1[n];
#pragma unroll
    for (int re = 0; re < 4; re++) {
#pragma unroll
      for (int r = 0; r < 4; r++) {
        int row = re * 16 + quad * 4 + r;
        sT[row * 264 + n] = (bf16_t)silu_f(acc[re][ce][r] + b1);
      }
    }
  }
  __syncthreads();

  f32x4 acc2[4][2];
#pragma unroll
  for (int i = 0; i < 4; i++)
#pragma unroll
    for (int j = 0; j < 2; j++) acc2[i][j] = zf;

  gemm_block<256, 264, 2>(sT, Wm2T, wave * 32, lr, quad, acc2);

#pragma unroll
  for (int ce = 0; ce < 2; ce++) {
    int n = wave * 32 + ce * 16 + lr;
    float b2 = bm2[n];
#pragma unroll
    for (int re = 0; re < 4; re++) {
#pragma unroll
      for (int r = 0; r < 4; r++) {
        int row = re * 16 + quad * 4 + r;
        int node = n0 + row;
        if (node < NN) {
          size_t idx = (size_t)node * CC + n;
          out[idx] = h1g[idx] + acc2[re][ce][r] + b2;
        }
      }
    }
  }
}

extern "C" void kernel_launch(void* const* d_in, const int* in_sizes, int n_in,
                              void* d_out, int out_size, void* d_ws, size_t ws_size,
                              hipStream_t stream) {
  const float* x    = (const float*)d_in[0];
  const float* h    = (const float*)d_in[1];
  const int*   ei   = (const int*)d_in[2];
  const float* We1  = (const float*)d_in[3];
  const float* be1  = (const float*)d_in[4];
  const float* We2  = (const float*)d_in[5];
  const float* be2  = (const float*)d_in[6];
  const float* Wn1  = (const float*)d_in[7];
  const float* bn1  = (const float*)d_in[8];
  const float* Wn2  = (const float*)d_in[9];
  const float* bn2  = (const float*)d_in[10];
  const float* Wm1  = (const float*)d_in[11];
  const float* bm1  = (const float*)d_in[12];
  const float* Wm2  = (const float*)d_in[13];
  const float* bm2  = (const float*)d_in[14];
  const float* g1   = (const float*)d_in[15];
  const float* bt1  = (const float*)d_in[16];
  const float* g2   = (const float*)d_in[17];
  const float* bt2  = (const float*)d_in[18];
  float* out = (float*)d_out;

  char* wp = (char*)d_ws;
  size_t off = 0;
  auto alloc = [&](size_t bytes) -> void* {
    void* p = wp + off;
    off = (off + bytes + 255) & ~(size_t)255;
    return p;
  };

  float*  hnf    = (float*)alloc((size_t)NN * CC * 4);
  bf16_t* hn16   = (bf16_t*)alloc((size_t)NN * CC * 2);
  float*  h1g    = (float*)alloc((size_t)NN * CC * 4);
  bf16_t* h2n16  = (bf16_t*)alloc((size_t)NN * CC * 2);
  float*  sums   = (float*)alloc((size_t)NN * HH * 4);
  int*    cnt    = (int*)alloc((size_t)NN * 4);
  bf16_t* mag16  = (bf16_t*)alloc((size_t)NN * HH * 2);
  int*    cursor = (int*)alloc((size_t)NN * 4);
  int*    perm   = (int*)alloc((size_t)EE * 4);
  bf16_t* We1T   = (bf16_t*)alloc(256 * 256 * 2);
  bf16_t* We2T   = (bf16_t*)alloc(256 * 256 * 2);
  bf16_t* Wn1T   = (bf16_t*)alloc(256 * 384 * 2);
  bf16_t* Wn2T   = (bf16_t*)alloc(128 * 256 * 2);
  bf16_t* Wm1T   = (bf16_t*)alloc(256 * 128 * 2);
  bf16_t* Wm2T   = (bf16_t*)alloc(128 * 256 * 2);

  hipMemsetAsync(sums, 0, (size_t)NN * HH * 4, stream);
  hipMemsetAsync(cnt, 0, (size_t)NN * 4, stream);

  // weight prep (reads first 256 rows of We1; row 256 handled via rank-1 epilogue)
  transpose_kernel<<<256, 256, 0, stream>>>(We1, We1T, 256, 256);
  transpose_kernel<<<256, 256, 0, stream>>>(We2, We2T, 256, 256);
  transpose_kernel<<<384, 256, 0, stream>>>(Wn1, Wn1T, 384, 256);
  transpose_kernel<<<128, 256, 0, stream>>>(Wn2, Wn2T, 256, 128);
  transpose_kernel<<<128, 256, 0, stream>>>(Wm1, Wm1T, 128, 256);
  transpose_kernel<<<128, 256, 0, stream>>>(Wm2, Wm2T, 256, 128);

  ln_kernel<<<NN, 64, 0, stream>>>(h, g1, bt1, hnf, hn16);

  count_kernel<<<EE / 256, 256, 0, stream>>>(ei, cnt);
  scan_kernel<<<1, 1024, 0, stream>>>(cnt, cursor);
  scatter_kernel<<<EE / 256, 256, 0, stream>>>(ei, cursor, perm);

  edge_mlp_kernel<<<EE / 64, 256, 0, stream>>>(x, ei, hn16, perm,
                                               We1T, We1 + 256 * 256, be1,
                                               We2T, be2, sums);

  divide_kernel<<<NN, 256, 0, stream>>>(sums, cnt, mag16);

  node_mlp1_kernel<<<(NN + 63) / 64, 256, 0, stream>>>(h, hnf, hn16, mag16,
                                                       Wn1T, bn1, Wn2T, bn2, h1g);

  ln_kernel<<<NN, 64, 0, stream>>>(h1g, g2, bt2, nullptr, h2n16);

  node_mlp2_kernel<<<(NN + 63) / 64, 256, 0, stream>>>(h2n16, Wm1T, bm1,
                                                       Wm2T, bm2, h1g, out);
}

// Round 2
// 411.136 us; speedup vs baseline: 1.2223x; 1.2223x over previous
//
#include <hip/hip_runtime.h>

#define NN 10000
#define CC 128
#define HH 256
#define EE 320000

typedef __bf16 bf16_t;
typedef __bf16 bf16x8 __attribute__((ext_vector_type(8)));
typedef __bf16 bf16x4 __attribute__((ext_vector_type(4)));
typedef float f32x4 __attribute__((ext_vector_type(4)));

__device__ __forceinline__ float silu_f(float v) {
#if __has_builtin(__builtin_amdgcn_rcpf)
  return v * __builtin_amdgcn_rcpf(1.0f + __expf(-v));
#else
  return v / (1.0f + __expf(-v));
#endif
}

// ---- GEMM slab helpers (16x16x32 bf16 MFMA) ----
// Fragment layouts (guide §3, m89-verified):
//   1st operand: lane holds A[m=lane&15][k=quad*8+j]
//   2nd operand: lane holds B[k=quad*8+j][n=lane&15]
//   C/D: col(n)=lane&15, row(m)=quad*4+reg

// A rows from LDS (stride SA), B rows from global row-major BT[n][k] (stride KD).
// acc[re][ce]: re tiles LDS rows (m), ce tiles BT rows (n).
template<int KD, int SA, int NT>
__device__ __forceinline__ void gemm_lg(const bf16_t* sAa, const bf16_t* __restrict__ BT,
                                        int nwavebase, int lr, int quad, f32x4 acc[4][NT]) {
  for (int kk = 0; kk < KD; kk += 32) {
    bf16x8 a[4]; bf16x8 b[NT];
#pragma unroll
    for (int re = 0; re < 4; re++)
      a[re] = *(const bf16x8*)(sAa + (re * 16 + lr) * SA + kk + quad * 8);
#pragma unroll
    for (int ce = 0; ce < NT; ce++)
      b[ce] = *(const bf16x8*)(BT + (size_t)(nwavebase + ce * 16 + lr) * KD + kk + quad * 8);
#pragma unroll
    for (int re = 0; re < 4; re++)
#pragma unroll
      for (int ce = 0; ce < NT; ce++)
        acc[re][ce] = __builtin_amdgcn_mfma_f32_16x16x32_bf16(a[re], b[ce], acc[re][ce], 0, 0, 0);
  }
}

// Swapped: A rows from global row-major AT[m][k] (stride KD), B rows from LDS (stride SB).
// acc[re][ce]: re tiles AT rows (m = channels), ce tiles LDS rows (n = edges).
template<int KD, int SB>
__device__ __forceinline__ void gemm_gl(const bf16_t* __restrict__ AT, int mwavebase,
                                        const bf16_t* sB, int lr, int quad, f32x4 acc[4][4]) {
  for (int kk = 0; kk < KD; kk += 32) {
    bf16x8 a[4]; bf16x8 b[4];
#pragma unroll
    for (int re = 0; re < 4; re++)
      a[re] = *(const bf16x8*)(AT + (size_t)(mwavebase + re * 16 + lr) * KD + kk + quad * 8);
#pragma unroll
    for (int ce = 0; ce < 4; ce++)
      b[ce] = *(const bf16x8*)(sB + (ce * 16 + lr) * SB + kk + quad * 8);
#pragma unroll
    for (int re = 0; re < 4; re++)
#pragma unroll
      for (int ce = 0; ce < 4; ce++)
        acc[re][ce] = __builtin_amdgcn_mfma_f32_16x16x32_bf16(a[re], b[ce], acc[re][ce], 0, 0, 0);
  }
}

// ---------- weight prep: f32 row-major (K x Nc) -> bf16 transposed (Nc x K) ----------
__global__ __launch_bounds__(256) void transpose_kernel(const float* __restrict__ src,
                                                        bf16_t* __restrict__ dst,
                                                        int K, int Nc) {
  int i = blockIdx.x * 256 + threadIdx.x;
  if (i < K * Nc) {
    int n = i / K;
    int k = i - n * K;
    dst[i] = (bf16_t)src[(size_t)k * Nc + n];
  }
}

// ---------- LayerNorm over 128 channels, 4 nodes/block ----------
__global__ __launch_bounds__(256) void ln_kernel(const float* __restrict__ src,
                                                 const float* __restrict__ g,
                                                 const float* __restrict__ b,
                                                 float* __restrict__ outf,
                                                 bf16_t* __restrict__ out16) {
  int node = blockIdx.x * 4 + (threadIdx.x >> 6);
  int lane = threadIdx.x & 63;
  if (node >= NN) return;
  size_t base = (size_t)node * CC;
  float v1 = src[base + lane], v2 = src[base + lane + 64];
  float s = v1 + v2, sq = v1 * v1 + v2 * v2;
#pragma unroll
  for (int o = 32; o > 0; o >>= 1) { s += __shfl_xor(s, o); sq += __shfl_xor(sq, o); }
  float mu = s * (1.0f / CC);
  float var = sq * (1.0f / CC) - mu * mu;
  float rs = rsqrtf(var + 1e-5f);
  float a1 = (v1 - mu) * rs * g[lane] + b[lane];
  float a2 = (v2 - mu) * rs * g[lane + 64] + b[lane + 64];
  if (outf) { outf[base + lane] = a1; outf[base + lane + 64] = a2; }
  out16[base + lane] = (bf16_t)a1;
  out16[base + lane + 64] = (bf16_t)a2;
}

// ---------- CSR build ----------
__global__ __launch_bounds__(256) void count_kernel(const int* __restrict__ ei, int* __restrict__ cnt) {
  int e = blockIdx.x * 256 + threadIdx.x;
  atomicAdd(&cnt[ei[EE + e]], 1);
}

__global__ __launch_bounds__(1024) void scan_kernel(const int* __restrict__ cnt, int* __restrict__ cursor) {
  __shared__ int wsum[16];
  int tid = threadIdx.x, wave = tid >> 6, lane = tid & 63;
  int base = 0;
  for (int start = 0; start < NN; start += 1024) {
    int i = start + tid;
    int v = (i < NN) ? cnt[i] : 0;
    int s = v;
#pragma unroll
    for (int off = 1; off < 64; off <<= 1) { int t = __shfl_up(s, off); if (lane >= off) s += t; }
    if (lane == 63) wsum[wave] = s;
    __syncthreads();
    if (tid < 16) {
      int ws = wsum[tid];
#pragma unroll
      for (int off = 1; off < 16; off <<= 1) { int t = __shfl_up(ws, off); if (tid >= off) ws += t; }
      wsum[tid] = ws;
    }
    __syncthreads();
    int wp = (wave > 0) ? wsum[wave - 1] : 0;
    if (i < NN) cursor[i] = base + wp + s - v;  // exclusive
    base += wsum[15];
    __syncthreads();
  }
}

__global__ __launch_bounds__(256) void scatter_kernel(const int* __restrict__ ei,
                                                      int* __restrict__ cursor,
                                                      int* __restrict__ perm) {
  int e = blockIdx.x * 256 + threadIdx.x;
  int c = ei[EE + e];
  int pos = atomicAdd(&cursor[c], 1);
  perm[pos] = e;
}

// ---------- fused edge MLP + segmented scatter ----------
// 64 CSR-ordered edges/block, 4 waves.
// GEMM1 SWAPPED (A=We1T global, B=features LDS) -> frag holds 4 consecutive
// channels per edge -> b64 m1 writes. GEMM2 normal; m2 stored TRANSPOSED
// [channel][edge] stride 72 (aliased in same buffer) -> b64 writes + b128
// reduction reads.
__global__ __launch_bounds__(256) void edge_mlp_kernel(
    const float* __restrict__ x, const int* __restrict__ ei,
    const bf16_t* __restrict__ hn16, const int* __restrict__ perm,
    const bf16_t* __restrict__ We1T, const float* __restrict__ We1last,
    const float* __restrict__ be1,
    const bf16_t* __restrict__ We2T, const float* __restrict__ be2,
    float* __restrict__ sums) {
  __shared__ __align__(16) bf16_t sBuf[256 * 72];  // 18432 elems: features/m1 (64x264) then m2T (256x72)
  __shared__ int sRow[64];
  __shared__ int sCol[64];
  __shared__ float sD[64];
  __shared__ float sCc[64];
  __shared__ unsigned long long sMask;
  int tid = threadIdx.x;
  int lane = tid & 63, wave = tid >> 6;
  int lr = lane & 15, quad = lane >> 4;
  int e0 = blockIdx.x * 64;

  if (tid < 64) {
    int eid = perm[e0 + tid];
    int r = ei[eid], c = ei[EE + eid];
    float dx = x[3 * r] - x[3 * c];
    float dy = x[3 * r + 1] - x[3 * c + 1];
    float dz = x[3 * r + 2] - x[3 * c + 2];
    float d = sqrtf(dx * dx + dy * dy + dz * dz);
    float cc = (d <= 5.0f) ? 0.5f * (cosf(d * 0.6283185307179586f) + 1.0f) : 0.0f;
    sRow[tid] = r; sCol[tid] = c; sD[tid] = d; sCc[tid] = cc;
  }
  __syncthreads();

  // segment-boundary bitmask (wave 0 only; needed after barrier 5)
  if (tid < 64) {
    int fl = (tid > 0) && (sCol[tid] != sCol[tid - 1]);
    unsigned long long m = __ballot(fl);
    if (tid == 0) sMask = m;
  }

  // gather A = [hn[row] | hn[col]] bf16, 16B chunks (stride 264)
#pragma unroll
  for (int i = 0; i < 8; i++) {
    int o = tid + i * 256;
    int e = o >> 5, q = o & 31;
    int srcrow = (q < 16) ? sRow[e] : sCol[e];
    uint4 v = *(const uint4*)(hn16 + (size_t)srcrow * CC + (q & 15) * 8);
    *(uint4*)(sBuf + e * 264 + (q & 15) * 8 + ((q < 16) ? 0 : 128)) = v;
  }
  __syncthreads();

  f32x4 zf = {0.f, 0.f, 0.f, 0.f};
  f32x4 acc[4][4];
#pragma unroll
  for (int i = 0; i < 4; i++)
#pragma unroll
    for (int j = 0; j < 4; j++) acc[i][j] = zf;

  // GEMM1 swapped: acc[re][ce] -> channel m = wave*64+re*16+quad*4+r, edge = ce*16+lr
  gemm_gl<256, 264>(We1T, wave * 64, sBuf, lr, quad, acc);
  __syncthreads();  // all waves done reading features

  // epilogue 1: m1[e][n] row-major stride 264, 4 consecutive channels -> b64
#pragma unroll
  for (int re = 0; re < 4; re++) {
    int nb = wave * 64 + re * 16 + quad * 4;
    f32x4 b1 = *(const f32x4*)(be1 + nb);
    f32x4 wl = *(const f32x4*)(We1last + nb);
#pragma unroll
    for (int ce = 0; ce < 4; ce++) {
      int e = ce * 16 + lr;
      float d = sD[e];
      bf16x4 o;
#pragma unroll
      for (int r = 0; r < 4; r++)
        o[r] = (bf16_t)silu_f(acc[re][ce][r] + b1[r] + d * wl[r]);
      *(bf16x4*)(sBuf + e * 264 + nb) = o;
    }
  }
  __syncthreads();

#pragma unroll
  for (int i = 0; i < 4; i++)
#pragma unroll
    for (int j = 0; j < 4; j++) acc[i][j] = zf;

  // GEMM2 normal: acc[re][ce] -> edge row = re*16+quad*4+r, channel n = wave*64+ce*16+lr
  gemm_lg<256, 264, 4>(sBuf, We2T, wave * 64, lr, quad, acc);
  __syncthreads();  // all waves done reading m1; safe to overwrite with m2T

  // epilogue 2: m2T[n][e] stride 72, 4 consecutive edges -> b64
#pragma unroll
  for (int re = 0; re < 4; re++) {
    int eb = re * 16 + quad * 4;
    f32x4 cc = *(const f32x4*)(sCc + eb);
#pragma unroll
    for (int ce = 0; ce < 4; ce++) {
      int n = wave * 64 + ce * 16 + lr;
      float b2 = be2[n];
      bf16x4 o;
#pragma unroll
      for (int r = 0; r < 4; r++)
        o[r] = (bf16_t)(silu_f(acc[re][ce][r] + b2) * cc[r]);
      *(bf16x4*)(sBuf + n * 72 + eb) = o;
    }
  }
  __syncthreads();

  // segmented reduction: thread tid owns channel tid; b128 reads of m2T row.
  {
    unsigned long long m = sMask;
    unsigned mlo = __builtin_amdgcn_readfirstlane((unsigned)m);
    unsigned mhi = __builtin_amdgcn_readfirstlane((unsigned)(m >> 32));
    const uint4* p = (const uint4*)(sBuf + (size_t)tid * 72);
    float a = 0.0f;
#pragma unroll
    for (int ci = 0; ci < 8; ci++) {
      uint4 c = p[ci];
      unsigned dw[4] = {c.x, c.y, c.z, c.w};
#pragma unroll
      for (int j = 0; j < 4; j++) {
        int e = ci * 8 + j * 2;
        unsigned bit0 = (e < 32) ? (mlo >> e) : (mhi >> (e - 32));
        if (bit0 & 1u) { atomicAdd(&sums[(size_t)sCol[e - 1] * HH + tid], a); a = 0.0f; }
        a += __uint_as_float(dw[j] << 16);
        int e1 = e + 1;
        unsigned bit1 = (e1 < 32) ? (mlo >> e1) : (mhi >> (e1 - 32));
        if (bit1 & 1u) { atomicAdd(&sums[(size_t)sCol[e1 - 1] * HH + tid], a); a = 0.0f; }
        a += __uint_as_float(dw[j] & 0xffff0000u);
      }
    }
    atomicAdd(&sums[(size_t)sCol[63] * HH + tid], a);
  }
}

// ---------- node MLP 1 (divide fused): hd = silu([hn|sums/cnt]@Wn1+bn1)@Wn2+bn2; h1 = h+hn+hd ----------
__global__ __launch_bounds__(256) void node_mlp1_kernel(
    const float* __restrict__ h, const float* __restrict__ hnf,
    const bf16_t* __restrict__ hn16, const float* __restrict__ sums,
    const int* __restrict__ cnt,
    const bf16_t* __restrict__ Wn1T, const float* __restrict__ bn1,
    const bf16_t* __restrict__ Wn2T, const float* __restrict__ bn2,
    float* __restrict__ h1g) {
  __shared__ __align__(16) bf16_t sA[64 * 392];
  __shared__ float sRc[64];
  int tid = threadIdx.x;
  int lane = tid & 63, wave = tid >> 6;
  int lr = lane & 15, quad = lane >> 4;
  int n0 = blockIdx.x * 64;

  if (tid < 64) {
    int node = n0 + tid;
    sRc[tid] = (node < NN) ? 1.0f / fmaxf((float)cnt[node], 1.0f) : 0.0f;
  }
  __syncthreads();

#pragma unroll
  for (int i = 0; i < 12; i++) {
    int o = tid + i * 256;
    int e = o / 48, q = o - e * 48;
    int node = n0 + e;
    if (node < NN && q < 16) {
      *(uint4*)(sA + e * 392 + q * 8) = *(const uint4*)(hn16 + (size_t)node * CC + q * 8);
    } else if (node < NN) {
      float rc = sRc[e];
      const float* sp = sums + (size_t)node * HH + (q - 16) * 8;
      bf16x8 bv;
#pragma unroll
      for (int k2 = 0; k2 < 8; k2++) bv[k2] = (bf16_t)(sp[k2] * rc);
      *(bf16x8*)(sA + e * 392 + q * 8) = bv;
    } else {
      uint4 z = {0u, 0u, 0u, 0u};
      *(uint4*)(sA + e * 392 + q * 8) = z;
    }
  }
  __syncthreads();

  f32x4 zf = {0.f, 0.f, 0.f, 0.f};
  f32x4 acc[4][4];
#pragma unroll
  for (int i = 0; i < 4; i++)
#pragma unroll
    for (int j = 0; j < 4; j++) acc[i][j] = zf;

  gemm_lg<384, 392, 4>(sA, Wn1T, wave * 64, lr, quad, acc);
  __syncthreads();

#pragma unroll
  for (int ce = 0; ce < 4; ce++) {
    int n = wave * 64 + ce * 16 + lr;
    float b1 = bn1[n];
#pragma unroll
    for (int re = 0; re < 4; re++) {
#pragma unroll
      for (int r = 0; r < 4; r++) {
        int row = re * 16 + quad * 4 + r;
        sA[row * 264 + n] = (bf16_t)silu_f(acc[re][ce][r] + b1);
      }
    }
  }
  __syncthreads();

  f32x4 acc2[4][2];
#pragma unroll
  for (int i = 0; i < 4; i++)
#pragma unroll
    for (int j = 0; j < 2; j++) acc2[i][j] = zf;

  gemm_lg<256, 264, 2>(sA, Wn2T, wave * 32, lr, quad, acc2);

#pragma unroll
  for (int ce = 0; ce < 2; ce++) {
    int n = wave * 32 + ce * 16 + lr;
    float b2 = bn2[n];
#pragma unroll
    for (int re = 0; re < 4; re++) {
#pragma unroll
      for (int r = 0; r < 4; r++) {
        int row = re * 16 + quad * 4 + r;
        int node = n0 + row;
        if (node < NN) {
          size_t idx = (size_t)node * CC + n;
          h1g[idx] = h[idx] + hnf[idx] + acc2[re][ce][r] + b2;
        }
      }
    }
  }
}

// ---------- node MLP 2: out = h1 + silu(LN2(h1)@Wm1+bm1)@Wm2+bm2 ----------
__global__ __launch_bounds__(256) void node_mlp2_kernel(
    const bf16_t* __restrict__ h2n16,
    const bf16_t* __restrict__ Wm1T, const float* __restrict__ bm1,
    const bf16_t* __restrict__ Wm2T, const float* __restrict__ bm2,
    const float* __restrict__ h1g, float* __restrict__ out) {
  __shared__ __align__(16) bf16_t sA[64 * 136];
  __shared__ __align__(16) bf16_t sT[64 * 264];
  int tid = threadIdx.x;
  int lane = tid & 63, wave = tid >> 6;
  int lr = lane & 15, quad = lane >> 4;
  int n0 = blockIdx.x * 64;

#pragma unroll
  for (int i = 0; i < 4; i++) {
    int o = tid + i * 256;
    int e = o >> 4, q = o & 15;
    int node = n0 + e;
    uint4 v = {0u, 0u, 0u, 0u};
    if (node < NN) v = *(const uint4*)(h2n16 + (size_t)node * CC + q * 8);
    *(uint4*)(sA + e * 136 + q * 8) = v;
  }
  __syncthreads();

  f32x4 zf = {0.f, 0.f, 0.f, 0.f};
  f32x4 acc[4][4];
#pragma unroll
  for (int i = 0; i < 4; i++)
#pragma unroll
    for (int j = 0; j < 4; j++) acc[i][j] = zf;

  gemm_lg<128, 136, 4>(sA, Wm1T, wave * 64, lr, quad, acc);

#pragma unroll
  for (int ce = 0; ce < 4; ce++) {
    int n = wave * 64 + ce * 16 + lr;
    float b1 = bm1[n];
#pragma unroll
    for (int re = 0; re < 4; re++) {
#pragma unroll
      for (int r = 0; r < 4; r++) {
        int row = re * 16 + quad * 4 + r;
        sT[row * 264 + n] = (bf16_t)silu_f(acc[re][ce][r] + b1);
      }
    }
  }
  __syncthreads();

  f32x4 acc2[4][2];
#pragma unroll
  for (int i = 0; i < 4; i++)
#pragma unroll
    for (int j = 0; j < 2; j++) acc2[i][j] = zf;

  gemm_lg<256, 264, 2>(sT, Wm2T, wave * 32, lr, quad, acc2);

#pragma unroll
  for (int ce = 0; ce < 2; ce++) {
    int n = wave * 32 + ce * 16 + lr;
    float b2 = bm2[n];
#pragma unroll
    for (int re = 0; re < 4; re++) {
#pragma unroll
      for (int r = 0; r < 4; r++) {
        int row = re * 16 + quad * 4 + r;
        int node = n0 + row;
        if (node < NN) {
          size_t idx = (size_t)node * CC + n;
          out[idx] = h1g[idx] + acc2[re][ce][r] + b2;
        }
      }
    }
  }
}

extern "C" void kernel_launch(void* const* d_in, const int* in_sizes, int n_in,
                              void* d_out, int out_size, void* d_ws, size_t ws_size,
                              hipStream_t stream) {
  const float* x    = (const float*)d_in[0];
  const float* h    = (const float*)d_in[1];
  const int*   ei   = (const int*)d_in[2];
  const float* We1  = (const float*)d_in[3];
  const float* be1  = (const float*)d_in[4];
  const float* We2  = (const float*)d_in[5];
  const float* be2  = (const float*)d_in[6];
  const float* Wn1  = (const float*)d_in[7];
  const float* bn1  = (const float*)d_in[8];
  const float* Wn2  = (const float*)d_in[9];
  const float* bn2  = (const float*)d_in[10];
  const float* Wm1  = (const float*)d_in[11];
  const float* bm1  = (const float*)d_in[12];
  const float* Wm2  = (const float*)d_in[13];
  const float* bm2  = (const float*)d_in[14];
  const float* g1   = (const float*)d_in[15];
  const float* bt1  = (const float*)d_in[16];
  const float* g2   = (const float*)d_in[17];
  const float* bt2  = (const float*)d_in[18];
  float* out = (float*)d_out;

  char* wp = (char*)d_ws;
  size_t off = 0;
  auto alloc = [&](size_t bytes) -> void* {
    void* p = wp + off;
    off = (off + bytes + 255) & ~(size_t)255;
    return p;
  };

  float*  hnf    = (float*)alloc((size_t)NN * CC * 4);
  bf16_t* hn16   = (bf16_t*)alloc((size_t)NN * CC * 2);
  float*  h1g    = (float*)alloc((size_t)NN * CC * 4);
  bf16_t* h2n16  = (bf16_t*)alloc((size_t)NN * CC * 2);
  float*  sums   = (float*)alloc((size_t)NN * HH * 4);
  int*    cnt    = (int*)alloc((size_t)NN * 4);
  int*    cursor = (int*)alloc((size_t)NN * 4);
  int*    perm   = (int*)alloc((size_t)EE * 4);
  bf16_t* We1T   = (bf16_t*)alloc(256 * 256 * 2);
  bf16_t* We2T   = (bf16_t*)alloc(256 * 256 * 2);
  bf16_t* Wn1T   = (bf16_t*)alloc(256 * 384 * 2);
  bf16_t* Wn2T   = (bf16_t*)alloc(128 * 256 * 2);
  bf16_t* Wm1T   = (bf16_t*)alloc(256 * 128 * 2);
  bf16_t* Wm2T   = (bf16_t*)alloc(128 * 256 * 2);

  hipMemsetAsync(sums, 0, (size_t)NN * HH * 4, stream);
  hipMemsetAsync(cnt, 0, (size_t)NN * 4, stream);

  transpose_kernel<<<256, 256, 0, stream>>>(We1, We1T, 256, 256);
  transpose_kernel<<<256, 256, 0, stream>>>(We2, We2T, 256, 256);
  transpose_kernel<<<384, 256, 0, stream>>>(Wn1, Wn1T, 384, 256);
  transpose_kernel<<<128, 256, 0, stream>>>(Wn2, Wn2T, 256, 128);
  transpose_kernel<<<128, 256, 0, stream>>>(Wm1, Wm1T, 128, 256);
  transpose_kernel<<<128, 256, 0, stream>>>(Wm2, Wm2T, 256, 128);

  ln_kernel<<<NN / 4, 256, 0, stream>>>(h, g1, bt1, hnf, hn16);

  count_kernel<<<EE / 256, 256, 0, stream>>>(ei, cnt);
  scan_kernel<<<1, 1024, 0, stream>>>(cnt, cursor);
  scatter_kernel<<<EE / 256, 256, 0, stream>>>(ei, cursor, perm);

  edge_mlp_kernel<<<EE / 64, 256, 0, stream>>>(x, ei, hn16, perm,
                                               We1T, We1 + 256 * 256, be1,
                                               We2T, be2, sums);

  node_mlp1_kernel<<<(NN + 63) / 64, 256, 0, stream>>>(h, hnf, hn16, sums, cnt,
                                                       Wn1T, bn1, Wn2T, bn2, h1g);

  ln_kernel<<<NN / 4, 256, 0, stream>>>(h1g, g2, bt2, nullptr, h2n16);

  node_mlp2_kernel<<<(NN + 63) / 64, 256, 0, stream>>>(h2n16, Wm1T, bm1,
                                                       Wm2T, bm2, h1g, out);
}

// Round 3
// 347.325 us; speedup vs baseline: 1.4468x; 1.1837x over previous
//
#include <hip/hip_runtime.h>

#define NN 10000
#define CC 128
#define HH 256
#define EE 320000
#define ETILE 128

typedef __bf16 bf16_t;
typedef __bf16 bf16x8 __attribute__((ext_vector_type(8)));
typedef __bf16 bf16x4 __attribute__((ext_vector_type(4)));
typedef __bf16 bf16x2 __attribute__((ext_vector_type(2)));
typedef float f32x4 __attribute__((ext_vector_type(4)));

__device__ __forceinline__ float silu_f(float v) {
#if __has_builtin(__builtin_amdgcn_rcpf)
  return v * __builtin_amdgcn_rcpf(1.0f + __expf(-v));
#else
  return v / (1.0f + __expf(-v));
#endif
}

// ---- GEMM slab helpers (16x16x32 bf16 MFMA) ----
// Fragment layouts (guide §3, m89-verified):
//   1st operand: lane holds A[m=lane&15][k=quad*8+j]
//   2nd operand: lane holds B[k=quad*8+j][n=lane&15]
//   C/D: col(n)=lane&15, row(m)=quad*4+reg

// A rows from LDS (stride SA, RE row-tiles), B rows from global row-major BT[n][k].
template<int RE, int KD, int SA, int NT>
__device__ __forceinline__ void gemm_lg(const bf16_t* sAa, const bf16_t* __restrict__ BT,
                                        int nwavebase, int lr, int quad, f32x4 acc[RE][NT]) {
  for (int kk = 0; kk < KD; kk += 32) {
    bf16x8 a[RE]; bf16x8 b[NT];
#pragma unroll
    for (int re = 0; re < RE; re++)
      a[re] = *(const bf16x8*)(sAa + (re * 16 + lr) * SA + kk + quad * 8);
#pragma unroll
    for (int ce = 0; ce < NT; ce++)
      b[ce] = *(const bf16x8*)(BT + (size_t)(nwavebase + ce * 16 + lr) * KD + kk + quad * 8);
#pragma unroll
    for (int re = 0; re < RE; re++)
#pragma unroll
      for (int ce = 0; ce < NT; ce++)
        acc[re][ce] = __builtin_amdgcn_mfma_f32_16x16x32_bf16(a[re], b[ce], acc[re][ce], 0, 0, 0);
  }
}

// Swapped: A rows (4 m-tiles) from global row-major AT[m][k], B rows (NE n-tiles) from LDS.
template<int KD, int SB, int NE>
__device__ __forceinline__ void gemm_gl(const bf16_t* __restrict__ AT, int mwavebase,
                                        const bf16_t* sB, int lr, int quad, f32x4 acc[4][NE]) {
  for (int kk = 0; kk < KD; kk += 32) {
    bf16x8 a[4]; bf16x8 b[NE];
#pragma unroll
    for (int re = 0; re < 4; re++)
      a[re] = *(const bf16x8*)(AT + (size_t)(mwavebase + re * 16 + lr) * KD + kk + quad * 8);
#pragma unroll
    for (int ce = 0; ce < NE; ce++)
      b[ce] = *(const bf16x8*)(sB + (ce * 16 + lr) * SB + kk + quad * 8);
#pragma unroll
    for (int re = 0; re < 4; re++)
#pragma unroll
      for (int ce = 0; ce < NE; ce++)
        acc[re][ce] = __builtin_amdgcn_mfma_f32_16x16x32_bf16(a[re], b[ce], acc[re][ce], 0, 0, 0);
  }
}

// ---------- all 6 weight transposes in ONE launch ----------
__global__ __launch_bounds__(256) void prep_weights(
    const float* __restrict__ We1, const float* __restrict__ We2,
    const float* __restrict__ Wn1, const float* __restrict__ Wn2,
    const float* __restrict__ Wm1, const float* __restrict__ Wm2,
    bf16_t* __restrict__ We1T, bf16_t* __restrict__ We2T,
    bf16_t* __restrict__ Wn1T, bf16_t* __restrict__ Wn2T,
    bf16_t* __restrict__ Wm1T, bf16_t* __restrict__ Wm2T) {
  int i = blockIdx.x * 256 + threadIdx.x;
  const float* src; bf16_t* dst; int K, Nc, idx;
  if      (i < 65536)  { src = We1; dst = We1T; K = 256; Nc = 256; idx = i; }
  else if (i < 131072) { src = We2; dst = We2T; K = 256; Nc = 256; idx = i - 65536; }
  else if (i < 229376) { src = Wn1; dst = Wn1T; K = 384; Nc = 256; idx = i - 131072; }
  else if (i < 262144) { src = Wn2; dst = Wn2T; K = 256; Nc = 128; idx = i - 229376; }
  else if (i < 294912) { src = Wm1; dst = Wm1T; K = 128; Nc = 256; idx = i - 262144; }
  else                 { src = Wm2; dst = Wm2T; K = 256; Nc = 128; idx = i - 294912; }
  int n = idx / K, k = idx - n * K;
  dst[idx] = (bf16_t)src[(size_t)k * Nc + n];
}

// ---------- LayerNorm1 over 128 channels, 4 nodes/block, bf16 out ----------
__global__ __launch_bounds__(256) void ln1_kernel(const float* __restrict__ src,
                                                  const float* __restrict__ g,
                                                  const float* __restrict__ b,
                                                  bf16_t* __restrict__ out16) {
  int node = blockIdx.x * 4 + (threadIdx.x >> 6);
  int lane = threadIdx.x & 63;
  size_t base = (size_t)node * CC;
  float v1 = src[base + lane], v2 = src[base + lane + 64];
  float s = v1 + v2, sq = v1 * v1 + v2 * v2;
#pragma unroll
  for (int o = 32; o > 0; o >>= 1) { s += __shfl_xor(s, o); sq += __shfl_xor(sq, o); }
  float mu = s * (1.0f / CC);
  float var = sq * (1.0f / CC) - mu * mu;
  float rs = rsqrtf(var + 1e-5f);
  out16[base + lane] = (bf16_t)((v1 - mu) * rs * g[lane] + b[lane]);
  out16[base + lane + 64] = (bf16_t)((v2 - mu) * rs * g[lane + 64] + b[lane + 64]);
}

// ---------- CSR build ----------
__global__ __launch_bounds__(256) void count_kernel(const int* __restrict__ ei, int* __restrict__ cnt) {
  int e = blockIdx.x * 256 + threadIdx.x;
  atomicAdd(&cnt[ei[EE + e]], 1);
}

__global__ __launch_bounds__(1024) void scan_kernel(const int* __restrict__ cnt, int* __restrict__ cursor) {
  __shared__ int wsum[16];
  int tid = threadIdx.x, wave = tid >> 6, lane = tid & 63;
  int base = 0;
  for (int start = 0; start < NN; start += 1024) {
    int i = start + tid;
    int v = (i < NN) ? cnt[i] : 0;
    int s = v;
#pragma unroll
    for (int off = 1; off < 64; off <<= 1) { int t = __shfl_up(s, off); if (lane >= off) s += t; }
    if (lane == 63) wsum[wave] = s;
    __syncthreads();
    if (tid < 16) {
      int ws = wsum[tid];
#pragma unroll
      for (int off = 1; off < 16; off <<= 1) { int t = __shfl_up(ws, off); if (tid >= off) ws += t; }
      wsum[tid] = ws;
    }
    __syncthreads();
    int wp = (wave > 0) ? wsum[wave - 1] : 0;
    if (i < NN) cursor[i] = base + wp + s - v;  // exclusive
    base += wsum[15];
    __syncthreads();
  }
}

// scatter + geometry: writes CSR-sorted {row, col, dist, cutoff} per edge
__global__ __launch_bounds__(256) void scatter_kernel(const int* __restrict__ ei,
                                                      const float* __restrict__ x,
                                                      int* __restrict__ cursor,
                                                      uint4* __restrict__ edat) {
  int e = blockIdx.x * 256 + threadIdx.x;
  int r = ei[e], c = ei[EE + e];
  float dx = x[3 * r] - x[3 * c];
  float dy = x[3 * r + 1] - x[3 * c + 1];
  float dz = x[3 * r + 2] - x[3 * c + 2];
  float d = sqrtf(dx * dx + dy * dy + dz * dz);
  float cc = (d <= 5.0f) ? 0.5f * (cosf(d * 0.6283185307179586f) + 1.0f) : 0.0f;
  int pos = atomicAdd(&cursor[c], 1);
  uint4 v = {(unsigned)r, (unsigned)c, __float_as_uint(d), __float_as_uint(cc)};
  edat[pos] = v;
}

// ---------- fused edge MLP + segmented scatter, 128-edge tiles ----------
__global__ __launch_bounds__(256, 2) void edge_mlp_kernel(
    const uint4* __restrict__ edat, const bf16_t* __restrict__ hn16,
    const bf16_t* __restrict__ We1T, const float* __restrict__ We1last,
    const float* __restrict__ be1,
    const bf16_t* __restrict__ We2T, const float* __restrict__ be2,
    float* __restrict__ sums) {
  // sBuf: features [128x264] -> m1 [128x264] -> m2T [256x130] (aliased, 67584 elems)
  __shared__ __align__(16) bf16_t sBuf[ETILE * 264];
  __shared__ int sRow[ETILE], sCol[ETILE];
  __shared__ float sD[ETILE], sCc[ETILE];
  __shared__ int sSegStart[ETILE + 1];
  __shared__ int sNseg;
  __shared__ unsigned long long sMask[2];
  int tid = threadIdx.x;
  int lane = tid & 63, wave = tid >> 6;
  int lr = lane & 15, quad = lane >> 4;
  int e0 = blockIdx.x * ETILE;  // 2500 blocks * 128 = EE exactly

  if (tid < ETILE) {
    uint4 v = edat[e0 + tid];
    sRow[tid] = (int)v.x; sCol[tid] = (int)v.y;
    sD[tid] = __uint_as_float(v.z); sCc[tid] = __uint_as_float(v.w);
  }
  __syncthreads();

  // segment-boundary ballot (waves 0,1)
  if (tid < ETILE) {
    int fl = (tid > 0) && (sCol[tid] != sCol[tid - 1]);
    unsigned long long m = __ballot(fl);
    if ((tid & 63) == 0) sMask[wave] = m;
  }

  // gather features = [hn[row] | hn[col]] bf16, 16B chunks (stride 264)
#pragma unroll
  for (int i = 0; i < 16; i++) {
    int o = tid + i * 256;
    int e = o >> 5, q = o & 31;
    int srcrow = (q < 16) ? sRow[e] : sCol[e];
    uint4 v = *(const uint4*)(hn16 + (size_t)srcrow * CC + (q & 15) * 8);
    *(uint4*)(sBuf + e * 264 + (q & 15) * 8 + ((q < 16) ? 0 : 128)) = v;
  }
  __syncthreads();

  f32x4 zf = {0.f, 0.f, 0.f, 0.f};
  {
    // GEMM1 swapped: channels (4 tiles, 64/wave) x edges (8 tiles = 128)
    f32x4 acc[4][8];
#pragma unroll
    for (int i = 0; i < 4; i++)
#pragma unroll
      for (int j = 0; j < 8; j++) acc[i][j] = zf;
    gemm_gl<256, 264, 8>(We1T, wave * 64, sBuf, lr, quad, acc);
    __syncthreads();  // all waves done reading features

    // epilogue 1: m1[e][n] stride 264, 4 consecutive channels -> b64
#pragma unroll
    for (int re = 0; re < 4; re++) {
      int nb = wave * 64 + re * 16 + quad * 4;
      f32x4 b1 = *(const f32x4*)(be1 + nb);
      f32x4 wl = *(const f32x4*)(We1last + nb);
#pragma unroll
      for (int ce = 0; ce < 8; ce++) {
        int e = ce * 16 + lr;
        float d = sD[e];
        bf16x4 o;
#pragma unroll
        for (int r = 0; r < 4; r++)
          o[r] = (bf16_t)silu_f(acc[re][ce][r] + b1[r] + d * wl[r]);
        *(bf16x4*)(sBuf + e * 264 + nb) = o;
      }
    }
  }
  __syncthreads();

  {
    // GEMM2 normal: edges (8 tiles) x channels (4 tiles, 64/wave)
    f32x4 acc[8][4];
#pragma unroll
    for (int i = 0; i < 8; i++)
#pragma unroll
      for (int j = 0; j < 4; j++) acc[i][j] = zf;
    gemm_lg<8, 256, 264, 4>(sBuf, We2T, wave * 64, lr, quad, acc);
    __syncthreads();  // all waves done reading m1; safe to alias m2T

    // epilogue 2: m2T[n][e], stride 130 (odd dwords -> conflict-free), b32 pairs
#pragma unroll
    for (int re = 0; re < 8; re++) {
      int eb = re * 16 + quad * 4;
      f32x4 cc = *(const f32x4*)(sCc + eb);
#pragma unroll
      for (int ce = 0; ce < 4; ce++) {
        int n = wave * 64 + ce * 16 + lr;
        float b2 = be2[n];
        float v0 = silu_f(acc[re][ce][0] + b2) * cc[0];
        float v1 = silu_f(acc[re][ce][1] + b2) * cc[1];
        float v2 = silu_f(acc[re][ce][2] + b2) * cc[2];
        float v3 = silu_f(acc[re][ce][3] + b2) * cc[3];
        bf16x2 p0 = {(bf16_t)v0, (bf16_t)v1};
        bf16x2 p1 = {(bf16_t)v2, (bf16_t)v3};
        *(bf16x2*)(sBuf + n * 130 + eb) = p0;
        *(bf16x2*)(sBuf + n * 130 + eb + 2) = p1;
      }
    }
  }

  // build segment list from ballot masks (uniform-loop reduction follows)
  if (tid < ETILE) {
    unsigned long long m0 = sMask[0], m1 = sMask[1];
    int fl = (tid > 0) && (sCol[tid] != sCol[tid - 1]);
    if (fl) {
      int l = tid & 63;
      unsigned long long below = ((tid < 64) ? m0 : m1) & ((1ull << l) - 1ull);
      int idx = __popcll(below) + ((tid >= 64) ? __popcll(m0) : 0) + 1;
      sSegStart[idx] = tid;
    }
    if (tid == 0) {
      int ns = 1 + __popcll(m0) + __popcll(m1);
      sNseg = ns;
      sSegStart[0] = 0;
      sSegStart[ns] = ETILE;
    }
  }
  __syncthreads();

  // segmented reduction: thread tid owns channel tid; uniform segment loop,
  // b32 reads of m2T row (stride 65 dwords -> all 32 banks, 2-way, free)
  {
    int nseg = sNseg;
    const bf16_t* rowp = sBuf + tid * 130;
    for (int s = 0; s < nseg; s++) {
      int lo = sSegStart[s], hi = sSegStart[s + 1];
      int colv = sCol[lo];
      float a = 0.0f;
      int e = lo;
      if (e & 1) { a += (float)rowp[e]; e++; }
      for (; e + 1 < hi; e += 2) {
        unsigned w = *(const unsigned*)(rowp + e);
        a += __uint_as_float(w << 16) + __uint_as_float(w & 0xffff0000u);
      }
      if (e < hi) a += (float)rowp[e];
      atomicAdd(&sums[(size_t)colv * HH + tid], a);
    }
  }
}

// ---------- fully fused node pipeline: 16 nodes/block, 625 blocks ----------
// [hn|m_aggr]@Wn1 -> silu -> @Wn2 -> h1 = h+hn+hd -> LN2 (in-LDS) ->
// @Wm1 -> silu -> @Wm2 -> out = h1 + ...
__global__ __launch_bounds__(256) void node_fused_kernel(
    const float* __restrict__ h, const bf16_t* __restrict__ hn16,
    const float* __restrict__ sums, const int* __restrict__ cnt,
    const bf16_t* __restrict__ Wn1T, const float* __restrict__ bn1,
    const bf16_t* __restrict__ Wn2T, const float* __restrict__ bn2,
    const float* __restrict__ g2, const float* __restrict__ bt2,
    const bf16_t* __restrict__ Wm1T, const float* __restrict__ bm1,
    const bf16_t* __restrict__ Wm2T, const float* __restrict__ bm2,
    float* __restrict__ out) {
  __shared__ __align__(16) bf16_t sA1[16 * 392];  // [hn|m_aggr], K=384
  __shared__ __align__(16) bf16_t sM[16 * 264];   // m1 hidden; later aliased as hidden2
  __shared__ __align__(16) float sH1[16 * 132];   // h1 (f32)
  __shared__ __align__(16) bf16_t sLn[16 * 136];  // LN2 output
  __shared__ float sRc[16];
  int tid = threadIdx.x;
  int lane = tid & 63, wave = tid >> 6;
  int lr = lane & 15, quad = lane >> 4;
  int n0 = blockIdx.x * 16;  // 625 * 16 = NN exactly

  if (tid < 16) sRc[tid] = 1.0f / fmaxf((float)cnt[n0 + tid], 1.0f);
  __syncthreads();

  // stage A1 = [hn16 | sums*rc] : 16 nodes x 48 16B-chunks
#pragma unroll
  for (int i = 0; i < 3; i++) {
    int o = tid + i * 256;
    int e = o / 48, q = o - e * 48;
    int node = n0 + e;
    if (q < 16) {
      *(uint4*)(sA1 + e * 392 + q * 8) = *(const uint4*)(hn16 + (size_t)node * CC + q * 8);
    } else {
      float rc = sRc[e];
      const float* sp = sums + (size_t)node * HH + (q - 16) * 8;
      bf16x8 bv;
#pragma unroll
      for (int k2 = 0; k2 < 8; k2++) bv[k2] = (bf16_t)(sp[k2] * rc);
      *(bf16x8*)(sA1 + e * 392 + (q - 16) * 8 + 128) = bv;
    }
  }
  __syncthreads();

  f32x4 zf = {0.f, 0.f, 0.f, 0.f};
  {  // GEMM1: 16 x 384 @ 384 x 256
    f32x4 acc[1][4];
#pragma unroll
    for (int j = 0; j < 4; j++) acc[0][j] = zf;
    gemm_lg<1, 384, 392, 4>(sA1, Wn1T, wave * 64, lr, quad, acc);
#pragma unroll
    for (int ce = 0; ce < 4; ce++) {
      int n = wave * 64 + ce * 16 + lr;
      float b1 = bn1[n];
#pragma unroll
      for (int r = 0; r < 4; r++)
        sM[(quad * 4 + r) * 264 + n] = (bf16_t)silu_f(acc[0][ce][r] + b1);
    }
  }
  __syncthreads();

  {  // GEMM2: 16 x 256 @ 256 x 128; h1 = h + hn + hd -> sH1
    f32x4 acc[1][2];
    acc[0][0] = zf; acc[0][1] = zf;
    gemm_lg<1, 256, 264, 2>(sM, Wn2T, wave * 32, lr, quad, acc);
#pragma unroll
    for (int ce = 0; ce < 2; ce++) {
      int n = wave * 32 + ce * 16 + lr;
      float b2 = bn2[n];
#pragma unroll
      for (int r = 0; r < 4; r++) {
        int node = quad * 4 + r;
        size_t idx = (size_t)(n0 + node) * CC + n;
        float hn_v = (float)sA1[node * 392 + n];
        sH1[node * 132 + n] = h[idx] + hn_v + acc[0][ce][r] + b2;
      }
    }
  }
  __syncthreads();

  {  // LN2 in-LDS: thread tid -> node tid>>4, channels (tid&15)*8 .. +7
    int node = tid >> 4, c0 = (tid & 15) * 8;
    f32x4 u0 = *(const f32x4*)(sH1 + node * 132 + c0);
    f32x4 u1 = *(const f32x4*)(sH1 + node * 132 + c0 + 4);
    float s = 0.f, sq = 0.f;
#pragma unroll
    for (int j = 0; j < 4; j++) { s += u0[j] + u1[j]; sq += u0[j] * u0[j] + u1[j] * u1[j]; }
#pragma unroll
    for (int o = 8; o > 0; o >>= 1) { s += __shfl_xor(s, o); sq += __shfl_xor(sq, o); }
    float mu = s * (1.0f / CC);
    float var = sq * (1.0f / CC) - mu * mu;
    float rs = rsqrtf(var + 1e-5f);
    f32x4 gg0 = *(const f32x4*)(g2 + c0), gg1 = *(const f32x4*)(g2 + c0 + 4);
    f32x4 bb0 = *(const f32x4*)(bt2 + c0), bb1 = *(const f32x4*)(bt2 + c0 + 4);
    bf16x8 ov;
#pragma unroll
    for (int j = 0; j < 4; j++) {
      ov[j] = (bf16_t)((u0[j] - mu) * rs * gg0[j] + bb0[j]);
      ov[j + 4] = (bf16_t)((u1[j] - mu) * rs * gg1[j] + bb1[j]);
    }
    *(bf16x8*)(sLn + node * 136 + c0) = ov;
  }
  __syncthreads();

  {  // GEMM3: 16 x 128 @ 128 x 256 -> silu -> sM (aliased as hidden2)
    f32x4 acc[1][4];
#pragma unroll
    for (int j = 0; j < 4; j++) acc[0][j] = zf;
    gemm_lg<1, 128, 136, 4>(sLn, Wm1T, wave * 64, lr, quad, acc);
#pragma unroll
    for (int ce = 0; ce < 4; ce++) {
      int n = wave * 64 + ce * 16 + lr;
      float b1 = bm1[n];
#pragma unroll
      for (int r = 0; r < 4; r++)
        sM[(quad * 4 + r) * 264 + n] = (bf16_t)silu_f(acc[0][ce][r] + b1);
    }
  }
  __syncthreads();

  {  // GEMM4: 16 x 256 @ 256 x 128; out = h1 + hd2
    f32x4 acc[1][2];
    acc[0][0] = zf; acc[0][1] = zf;
    gemm_lg<1, 256, 264, 2>(sM, Wm2T, wave * 32, lr, quad, acc);
#pragma unroll
    for (int ce = 0; ce < 2; ce++) {
      int n = wave * 32 + ce * 16 + lr;
      float b2 = bm2[n];
#pragma unroll
      for (int r = 0; r < 4; r++) {
        int node = quad * 4 + r;
        size_t idx = (size_t)(n0 + node) * CC + n;
        out[idx] = sH1[node * 132 + n] + acc[0][ce][r] + b2;
      }
    }
  }
}

extern "C" void kernel_launch(void* const* d_in, const int* in_sizes, int n_in,
                              void* d_out, int out_size, void* d_ws, size_t ws_size,
                              hipStream_t stream) {
  const float* x    = (const float*)d_in[0];
  const float* h    = (const float*)d_in[1];
  const int*   ei   = (const int*)d_in[2];
  const float* We1  = (const float*)d_in[3];
  const float* be1  = (const float*)d_in[4];
  const float* We2  = (const float*)d_in[5];
  const float* be2  = (const float*)d_in[6];
  const float* Wn1  = (const float*)d_in[7];
  const float* bn1  = (const float*)d_in[8];
  const float* Wn2  = (const float*)d_in[9];
  const float* bn2  = (const float*)d_in[10];
  const float* Wm1  = (const float*)d_in[11];
  const float* bm1  = (const float*)d_in[12];
  const float* Wm2  = (const float*)d_in[13];
  const float* bm2  = (const float*)d_in[14];
  const float* g1   = (const float*)d_in[15];
  const float* bt1  = (const float*)d_in[16];
  const float* g2   = (const float*)d_in[17];
  const float* bt2  = (const float*)d_in[18];
  float* out = (float*)d_out;

  char* wp = (char*)d_ws;
  size_t off = 0;
  auto alloc = [&](size_t bytes) -> void* {
    void* p = wp + off;
    off = (off + bytes + 255) & ~(size_t)255;
    return p;
  };

  bf16_t* hn16   = (bf16_t*)alloc((size_t)NN * CC * 2);
  float*  sums   = (float*)alloc((size_t)NN * HH * 4);
  int*    cnt    = (int*)alloc((size_t)NN * 4);
  int*    cursor = (int*)alloc((size_t)NN * 4);
  uint4*  edat   = (uint4*)alloc((size_t)EE * 16);
  bf16_t* We1T   = (bf16_t*)alloc(256 * 256 * 2);
  bf16_t* We2T   = (bf16_t*)alloc(256 * 256 * 2);
  bf16_t* Wn1T   = (bf16_t*)alloc(256 * 384 * 2);
  bf16_t* Wn2T   = (bf16_t*)alloc(128 * 256 * 2);
  bf16_t* Wm1T   = (bf16_t*)alloc(256 * 128 * 2);
  bf16_t* Wm2T   = (bf16_t*)alloc(128 * 256 * 2);

  hipMemsetAsync(sums, 0, (size_t)NN * HH * 4, stream);
  hipMemsetAsync(cnt, 0, (size_t)NN * 4, stream);

  prep_weights<<<1280, 256, 0, stream>>>(We1, We2, Wn1, Wn2, Wm1, Wm2,
                                         We1T, We2T, Wn1T, Wn2T, Wm1T, Wm2T);

  ln1_kernel<<<NN / 4, 256, 0, stream>>>(h, g1, bt1, hn16);

  count_kernel<<<EE / 256, 256, 0, stream>>>(ei, cnt);
  scan_kernel<<<1, 1024, 0, stream>>>(cnt, cursor);
  scatter_kernel<<<EE / 256, 256, 0, stream>>>(ei, x, cursor, edat);

  edge_mlp_kernel<<<EE / ETILE, 256, 0, stream>>>(edat, hn16,
                                                  We1T, We1 + 256 * 256, be1,
                                                  We2T, be2, sums);

  node_fused_kernel<<<NN / 16, 256, 0, stream>>>(h, hn16, sums, cnt,
                                                 Wn1T, bn1, Wn2T, bn2,
                                                 g2, bt2, Wm1T, bm1, Wm2T, bm2, out);
}

// Round 4
// 311.662 us; speedup vs baseline: 1.6124x; 1.1144x over previous
//
#include <hip/hip_runtime.h>

#define NN 10000
#define CC 128
#define HH 256
#define EE 320000
#define ETILE 96
#define EBLOCKS 3334  // ceil(EE/96); pad = 3334*96 - EE = 64 zero-edges

typedef __bf16 bf16_t;
typedef __bf16 bf16x8 __attribute__((ext_vector_type(8)));
typedef __bf16 bf16x4 __attribute__((ext_vector_type(4)));
typedef float f32x4 __attribute__((ext_vector_type(4)));

__device__ __forceinline__ float silu_f(float v) {
#if __has_builtin(__builtin_amdgcn_rcpf)
  return v * __builtin_amdgcn_rcpf(1.0f + __expf(-v));
#else
  return v / (1.0f + __expf(-v));
#endif
}

// ---- GEMM slab helper (16x16x32 bf16 MFMA) ----
// Fragment layouts (guide §3, m89-verified):
//   1st operand: lane holds A[m=lane&15][k=quad*8+j]
//   2nd operand: lane holds B[k=quad*8+j][n=lane&15]
//   C/D: col(n)=lane&15, row(m)=quad*4+reg
template<int RE, int KD, int SA, int NT>
__device__ __forceinline__ void gemm_lg(const bf16_t* sAa, const bf16_t* __restrict__ BT,
                                        int nwavebase, int lr, int quad, f32x4 acc[RE][NT]) {
  for (int kk = 0; kk < KD; kk += 32) {
    bf16x8 a[RE]; bf16x8 b[NT];
#pragma unroll
    for (int re = 0; re < RE; re++)
      a[re] = *(const bf16x8*)(sAa + (re * 16 + lr) * SA + kk + quad * 8);
#pragma unroll
    for (int ce = 0; ce < NT; ce++)
      b[ce] = *(const bf16x8*)(BT + (size_t)(nwavebase + ce * 16 + lr) * KD + kk + quad * 8);
#pragma unroll
    for (int re = 0; re < RE; re++)
#pragma unroll
      for (int ce = 0; ce < NT; ce++)
        acc[re][ce] = __builtin_amdgcn_mfma_f32_16x16x32_bf16(a[re], b[ce], acc[re][ce], 0, 0, 0);
  }
}

// ---------- all 6 weight transposes in ONE launch ----------
__global__ __launch_bounds__(256) void prep_weights(
    const float* __restrict__ We1, const float* __restrict__ We2,
    const float* __restrict__ Wn1, const float* __restrict__ Wn2,
    const float* __restrict__ Wm1, const float* __restrict__ Wm2,
    bf16_t* __restrict__ We1T, bf16_t* __restrict__ We2T,
    bf16_t* __restrict__ Wn1T, bf16_t* __restrict__ Wn2T,
    bf16_t* __restrict__ Wm1T, bf16_t* __restrict__ Wm2T) {
  int i = blockIdx.x * 256 + threadIdx.x;
  const float* src; bf16_t* dst; int K, Nc, idx;
  if      (i < 65536)  { src = We1; dst = We1T; K = 256; Nc = 256; idx = i; }
  else if (i < 131072) { src = We2; dst = We2T; K = 256; Nc = 256; idx = i - 65536; }
  else if (i < 229376) { src = Wn1; dst = Wn1T; K = 384; Nc = 256; idx = i - 131072; }
  else if (i < 262144) { src = Wn2; dst = Wn2T; K = 256; Nc = 128; idx = i - 229376; }
  else if (i < 294912) { src = Wm1; dst = Wm1T; K = 128; Nc = 256; idx = i - 262144; }
  else                 { src = Wm2; dst = Wm2T; K = 256; Nc = 128; idx = i - 294912; }
  int n = idx / K, k = idx - n * K;
  dst[idx] = (bf16_t)src[(size_t)k * Nc + n];
}

// ---------- fused LN1 + P/Q precompute ----------
// hn = LN(h,g1,bt1) -> hn16 (global, bf16)
// PQ[n][0:256]   = hn[n] @ We1[0:128,:]   + be1   (P, be1 folded)
// PQ[n][256:512] = hn[n] @ We1[128:256,:]         (Q)
__global__ __launch_bounds__(256, 3) void node_pre_kernel(
    const float* __restrict__ h, const float* __restrict__ g1,
    const float* __restrict__ bt1,
    const bf16_t* __restrict__ We1T, const float* __restrict__ be1,
    bf16_t* __restrict__ hn16, bf16_t* __restrict__ PQ) {
  __shared__ __align__(16) float sHf[64 * 132];   // 33792 B
  __shared__ __align__(16) bf16_t sHn[64 * 136];  // 17408 B
  int tid = threadIdx.x;
  int lane = tid & 63, wave = tid >> 6;
  int lr = lane & 15, quad = lane >> 4;
  int n0 = blockIdx.x * 64;  // 157 blocks, guard

  // stage h (f32): 64 nodes x 32 f32x4 chunks
#pragma unroll
  for (int i = 0; i < 8; i++) {
    int o = tid + i * 256;
    int node = o >> 5, q = o & 31;
    f32x4 v = {0.f, 0.f, 0.f, 0.f};
    if (n0 + node < NN) v = *(const f32x4*)(h + (size_t)(n0 + node) * CC + q * 4);
    *(f32x4*)(sHf + node * 132 + q * 4) = v;
  }
  __syncthreads();

  // LN: thread handles node tid>>2, channels (tid&3)*32..+31
  {
    int node = tid >> 2, c0 = (tid & 3) * 32;
    f32x4 u[8];
    float s = 0.f, sq = 0.f;
#pragma unroll
    for (int j = 0; j < 8; j++) {
      u[j] = *(const f32x4*)(sHf + node * 132 + c0 + j * 4);
#pragma unroll
      for (int r = 0; r < 4; r++) { s += u[j][r]; sq += u[j][r] * u[j][r]; }
    }
    s += __shfl_xor(s, 1); sq += __shfl_xor(sq, 1);
    s += __shfl_xor(s, 2); sq += __shfl_xor(sq, 2);
    float mu = s * (1.0f / CC);
    float var = sq * (1.0f / CC) - mu * mu;
    float rs = rsqrtf(var + 1e-5f);
    bool live = (n0 + node) < NN;
#pragma unroll
    for (int j2 = 0; j2 < 4; j2++) {
      f32x4 gg0 = *(const f32x4*)(g1 + c0 + j2 * 8);
      f32x4 gg1 = *(const f32x4*)(g1 + c0 + j2 * 8 + 4);
      f32x4 bb0 = *(const f32x4*)(bt1 + c0 + j2 * 8);
      f32x4 bb1 = *(const f32x4*)(bt1 + c0 + j2 * 8 + 4);
      bf16x8 ov;
#pragma unroll
      for (int r = 0; r < 4; r++) {
        ov[r] = (bf16_t)((u[j2 * 2][r] - mu) * rs * gg0[r] + bb0[r]);
        ov[r + 4] = (bf16_t)((u[j2 * 2 + 1][r] - mu) * rs * gg1[r] + bb1[r]);
      }
      *(bf16x8*)(sHn + node * 136 + c0 + j2 * 8) = ov;
      if (live) *(bf16x8*)(hn16 + (size_t)(n0 + node) * CC + c0 + j2 * 8) = ov;
    }
  }
  __syncthreads();

  // PQ GEMMs (swapped): A = We1T rows (channels), B = sHn (nodes). K=128 per pass.
  f32x4 zf = {0.f, 0.f, 0.f, 0.f};
#pragma unroll
  for (int p = 0; p < 2; p++) {
    f32x4 acc[4][4];
#pragma unroll
    for (int i = 0; i < 4; i++)
#pragma unroll
      for (int j = 0; j < 4; j++) acc[i][j] = zf;
    for (int kk = 0; kk < 128; kk += 32) {
      bf16x8 a[4]; bf16x8 b[4];
#pragma unroll
      for (int re = 0; re < 4; re++)
        a[re] = *(const bf16x8*)(We1T + (size_t)(wave * 64 + re * 16 + lr) * 256 + p * 128 + kk + quad * 8);
#pragma unroll
      for (int ce = 0; ce < 4; ce++)
        b[ce] = *(const bf16x8*)(sHn + (ce * 16 + lr) * 136 + kk + quad * 8);
#pragma unroll
      for (int re = 0; re < 4; re++)
#pragma unroll
        for (int ce = 0; ce < 4; ce++)
          acc[re][ce] = __builtin_amdgcn_mfma_f32_16x16x32_bf16(a[re], b[ce], acc[re][ce], 0, 0, 0);
    }
    // C: col=node(ce*16+lr), row=channel(wave*64+re*16+quad*4+r) -> bf16x4 stores
#pragma unroll
    for (int re = 0; re < 4; re++) {
      int cbase = wave * 64 + re * 16 + quad * 4;
      f32x4 bb = zf;
      if (p == 0) bb = *(const f32x4*)(be1 + cbase);
#pragma unroll
      for (int ce = 0; ce < 4; ce++) {
        int node = ce * 16 + lr;
        if (n0 + node < NN) {
          bf16x4 o;
#pragma unroll
          for (int r = 0; r < 4; r++) o[r] = (bf16_t)(acc[re][ce][r] + bb[r]);
          *(bf16x4*)(PQ + (size_t)(n0 + node) * 512 + p * 256 + cbase) = o;
        }
      }
    }
  }
}

// ---------- CSR build ----------
__global__ __launch_bounds__(256) void count_kernel(const int* __restrict__ ei, int* __restrict__ cnt) {
  int e = blockIdx.x * 256 + threadIdx.x;
  atomicAdd(&cnt[ei[EE + e]], 1);
}

__global__ __launch_bounds__(1024) void scan_kernel(const int* __restrict__ cnt, int* __restrict__ cursor) {
  __shared__ int wsum[16];
  int tid = threadIdx.x, wave = tid >> 6, lane = tid & 63;
  int base = 0;
  for (int start = 0; start < NN; start += 1024) {
    int i = start + tid;
    int v = (i < NN) ? cnt[i] : 0;
    int s = v;
#pragma unroll
    for (int off = 1; off < 64; off <<= 1) { int t = __shfl_up(s, off); if (lane >= off) s += t; }
    if (lane == 63) wsum[wave] = s;
    __syncthreads();
    if (tid < 16) {
      int ws = wsum[tid];
#pragma unroll
      for (int off = 1; off < 16; off <<= 1) { int t = __shfl_up(ws, off); if (tid >= off) ws += t; }
      wsum[tid] = ws;
    }
    __syncthreads();
    int wp = (wave > 0) ? wsum[wave - 1] : 0;
    if (i < NN) cursor[i] = base + wp + s - v;  // exclusive
    base += wsum[15];
    __syncthreads();
  }
}

// scatter + geometry: CSR-sorted {row, col, dist, cutoff}
__global__ __launch_bounds__(256) void scatter_kernel(const int* __restrict__ ei,
                                                      const float* __restrict__ x,
                                                      int* __restrict__ cursor,
                                                      uint4* __restrict__ edat) {
  int e = blockIdx.x * 256 + threadIdx.x;
  int r = ei[e], c = ei[EE + e];
  float dx = x[3 * r] - x[3 * c];
  float dy = x[3 * r + 1] - x[3 * c + 1];
  float dz = x[3 * r + 2] - x[3 * c + 2];
  float d = sqrtf(dx * dx + dy * dy + dz * dz);
  float cc = (d <= 5.0f) ? 0.5f * (cosf(d * 0.6283185307179586f) + 1.0f) : 0.0f;
  int pos = atomicAdd(&cursor[c], 1);
  uint4 v = {(unsigned)r, (unsigned)c, __float_as_uint(d), __float_as_uint(cc)};
  edat[pos] = v;
}

// ---------- edge kernel v4: gather-silu -> GEMM2 -> register segmented reduce ----------
__global__ __launch_bounds__(256, 3) void edge_mlp_kernel(
    const uint4* __restrict__ edat, const bf16_t* __restrict__ PQ,
    const float* __restrict__ We1last,
    const bf16_t* __restrict__ We2T, const float* __restrict__ be2,
    float* __restrict__ sums) {
  __shared__ __align__(16) bf16_t sM1[ETILE * 264];  // 50688 B
  __shared__ int sRow[ETILE], sCol[ETILE];
  __shared__ float sD[ETILE], sCc[ETILE];
  __shared__ unsigned long long sMask[2];
  int tid = threadIdx.x;
  int lane = tid & 63, wave = tid >> 6;
  int lr = lane & 15, quad = lane >> 4;
  int e0 = blockIdx.x * ETILE;

  if (tid < ETILE) {
    uint4 v = edat[e0 + tid];
    sRow[tid] = (int)v.x; sCol[tid] = (int)v.y;
    sD[tid] = __uint_as_float(v.z); sCc[tid] = __uint_as_float(v.w);
  }
  __syncthreads();

  // segment-boundary ballot (waves 0,1 only; bits for e=64..95 live in low 32 of sMask[1])
  if (tid < ETILE) {
    int fl = (tid > 0) && (sCol[tid] != sCol[tid - 1]);
    unsigned long long m = __ballot(fl);
    if ((tid & 63) == 0) sMask[wave] = m;
  }

  // gather-compute m1[e][k] = silu(P[row][k] + Q[col][k] + d*wl[k]) (be1 folded in P)
#pragma unroll
  for (int i = 0; i < ETILE * 32 / 256; i++) {  // 12
    int o = tid + i * 256;
    int e = o >> 5, q = o & 31;
    int k0 = q * 8;
    int row = sRow[e], col = sCol[e];
    float d = sD[e];
    bf16x8 pv = *(const bf16x8*)(PQ + (size_t)row * 512 + k0);
    bf16x8 qv = *(const bf16x8*)(PQ + (size_t)col * 512 + 256 + k0);
    f32x4 wl0 = *(const f32x4*)(We1last + k0);
    f32x4 wl1 = *(const f32x4*)(We1last + k0 + 4);
    bf16x8 m;
#pragma unroll
    for (int j = 0; j < 4; j++) {
      m[j] = (bf16_t)silu_f((float)pv[j] + (float)qv[j] + d * wl0[j]);
      m[j + 4] = (bf16_t)silu_f((float)pv[j + 4] + (float)qv[j + 4] + d * wl1[j]);
    }
    *(bf16x8*)(sM1 + e * 264 + k0) = m;
  }
  __syncthreads();

  // GEMM2: m1 (96 edges x 256) @ We2 -> wave's 64 channels
  f32x4 zf = {0.f, 0.f, 0.f, 0.f};
  f32x4 acc[6][4];
#pragma unroll
  for (int i = 0; i < 6; i++)
#pragma unroll
    for (int j = 0; j < 4; j++) acc[i][j] = zf;
  gemm_lg<6, 256, 264, 4>(sM1, We2T, wave * 64, lr, quad, acc);

  // in-register epilogue: v = silu(acc + be2)*cc  (edge e = re*16+quad*4+r)
  float be2v[4];
#pragma unroll
  for (int ce = 0; ce < 4; ce++) be2v[ce] = be2[wave * 64 + ce * 16 + lr];
#pragma unroll
  for (int re = 0; re < 6; re++) {
    f32x4 cc = *(const f32x4*)(sCc + re * 16 + quad * 4);
#pragma unroll
    for (int ce = 0; ce < 4; ce++)
#pragma unroll
      for (int r = 0; r < 4; r++)
        acc[re][ce][r] = silu_f(acc[re][ce][r] + be2v[ce]) * cc[r];
  }

  // register segmented reduction over edges; wave-uniform segment walk
  {
    unsigned long long w0 = sMask[0];
    unsigned long long w1 = sMask[1];
    int lo = 0;
    while (lo < ETILE) {
      int hi;
      unsigned long long t = (lo < 63) ? (w0 & (~0ull << (lo + 1))) : 0ull;
      if (t) {
        hi = __ffsll((long long)t) - 1;
      } else {
        unsigned long long mk = (lo + 1 > 64) ? (~0ull << (lo + 1 - 64)) : ~0ull;
        unsigned long long t1 = w1 & mk;
        hi = t1 ? 64 + __ffsll((long long)t1) - 1 : ETILE;
      }
      f32x4 tv = zf;
#pragma unroll
      for (int re = 0; re < 6; re++) {
        int eb = re * 16 + quad * 4;
#pragma unroll
        for (int r = 0; r < 4; r++) {
          int e = eb + r;
          bool in = (e >= lo) && (e < hi);
#pragma unroll
          for (int ce = 0; ce < 4; ce++)
            tv[ce] += in ? acc[re][ce][r] : 0.0f;
        }
      }
#pragma unroll
      for (int ce = 0; ce < 4; ce++) {
        tv[ce] += __shfl_xor(tv[ce], 16);
        tv[ce] += __shfl_xor(tv[ce], 32);
      }
      if (quad == 0) {
        int colv = sCol[lo];
#pragma unroll
        for (int ce = 0; ce < 4; ce++)
          atomicAdd(&sums[(size_t)colv * HH + wave * 64 + ce * 16 + lr], tv[ce]);
      }
      lo = hi;
    }
  }
}

// ---------- fully fused node pipeline: 16 nodes/block, 625 blocks ----------
__global__ __launch_bounds__(256) void node_fused_kernel(
    const float* __restrict__ h, const bf16_t* __restrict__ hn16,
    const float* __restrict__ sums, const int* __restrict__ cnt,
    const bf16_t* __restrict__ Wn1T, const float* __restrict__ bn1,
    const bf16_t* __restrict__ Wn2T, const float* __restrict__ bn2,
    const float* __restrict__ g2, const float* __restrict__ bt2,
    const bf16_t* __restrict__ Wm1T, const float* __restrict__ bm1,
    const bf16_t* __restrict__ Wm2T, const float* __restrict__ bm2,
    float* __restrict__ out) {
  __shared__ __align__(16) bf16_t sA1[16 * 392];
  __shared__ __align__(16) bf16_t sM[16 * 264];
  __shared__ __align__(16) float sH1[16 * 132];
  __shared__ __align__(16) bf16_t sLn[16 * 136];
  __shared__ float sRc[16];
  int tid = threadIdx.x;
  int lane = tid & 63, wave = tid >> 6;
  int lr = lane & 15, quad = lane >> 4;
  int n0 = blockIdx.x * 16;

  if (tid < 16) sRc[tid] = 1.0f / fmaxf((float)cnt[n0 + tid], 1.0f);
  __syncthreads();

#pragma unroll
  for (int i = 0; i < 3; i++) {
    int o = tid + i * 256;
    int e = o / 48, q = o - e * 48;
    int node = n0 + e;
    if (q < 16) {
      *(uint4*)(sA1 + e * 392 + q * 8) = *(const uint4*)(hn16 + (size_t)node * CC + q * 8);
    } else {
      float rc = sRc[e];
      const float* sp = sums + (size_t)node * HH + (q - 16) * 8;
      bf16x8 bv;
#pragma unroll
      for (int k2 = 0; k2 < 8; k2++) bv[k2] = (bf16_t)(sp[k2] * rc);
      *(bf16x8*)(sA1 + e * 392 + (q - 16) * 8 + 128) = bv;
    }
  }
  __syncthreads();

  f32x4 zf = {0.f, 0.f, 0.f, 0.f};
  {
    f32x4 acc[1][4];
#pragma unroll
    for (int j = 0; j < 4; j++) acc[0][j] = zf;
    gemm_lg<1, 384, 392, 4>(sA1, Wn1T, wave * 64, lr, quad, acc);
#pragma unroll
    for (int ce = 0; ce < 4; ce++) {
      int n = wave * 64 + ce * 16 + lr;
      float b1 = bn1[n];
#pragma unroll
      for (int r = 0; r < 4; r++)
        sM[(quad * 4 + r) * 264 + n] = (bf16_t)silu_f(acc[0][ce][r] + b1);
    }
  }
  __syncthreads();

  {
    f32x4 acc[1][2];
    acc[0][0] = zf; acc[0][1] = zf;
    gemm_lg<1, 256, 264, 2>(sM, Wn2T, wave * 32, lr, quad, acc);
#pragma unroll
    for (int ce = 0; ce < 2; ce++) {
      int n = wave * 32 + ce * 16 + lr;
      float b2 = bn2[n];
#pragma unroll
      for (int r = 0; r < 4; r++) {
        int node = quad * 4 + r;
        size_t idx = (size_t)(n0 + node) * CC + n;
        float hn_v = (float)sA1[node * 392 + n];
        sH1[node * 132 + n] = h[idx] + hn_v + acc[0][ce][r] + b2;
      }
    }
  }
  __syncthreads();

  {
    int node = tid >> 4, c0 = (tid & 15) * 8;
    f32x4 u0 = *(const f32x4*)(sH1 + node * 132 + c0);
    f32x4 u1 = *(const f32x4*)(sH1 + node * 132 + c0 + 4);
    float s = 0.f, sq = 0.f;
#pragma unroll
    for (int j = 0; j < 4; j++) { s += u0[j] + u1[j]; sq += u0[j] * u0[j] + u1[j] * u1[j]; }
#pragma unroll
    for (int o = 8; o > 0; o >>= 1) { s += __shfl_xor(s, o); sq += __shfl_xor(sq, o); }
    float mu = s * (1.0f / CC);
    float var = sq * (1.0f / CC) - mu * mu;
    float rs = rsqrtf(var + 1e-5f);
    f32x4 gg0 = *(const f32x4*)(g2 + c0), gg1 = *(const f32x4*)(g2 + c0 + 4);
    f32x4 bb0 = *(const f32x4*)(bt2 + c0), bb1 = *(const f32x4*)(bt2 + c0 + 4);
    bf16x8 ov;
#pragma unroll
    for (int j = 0; j < 4; j++) {
      ov[j] = (bf16_t)((u0[j] - mu) * rs * gg0[j] + bb0[j]);
      ov[j + 4] = (bf16_t)((u1[j] - mu) * rs * gg1[j] + bb1[j]);
    }
    *(bf16x8*)(sLn + node * 136 + c0) = ov;
  }
  __syncthreads();

  {
    f32x4 acc[1][4];
#pragma unroll
    for (int j = 0; j < 4; j++) acc[0][j] = zf;
    gemm_lg<1, 128, 136, 4>(sLn, Wm1T, wave * 64, lr, quad, acc);
#pragma unroll
    for (int ce = 0; ce < 4; ce++) {
      int n = wave * 64 + ce * 16 + lr;
      float b1 = bm1[n];
#pragma unroll
      for (int r = 0; r < 4; r++)
        sM[(quad * 4 + r) * 264 + n] = (bf16_t)silu_f(acc[0][ce][r] + b1);
    }
  }
  __syncthreads();

  {
    f32x4 acc[1][2];
    acc[0][0] = zf; acc[0][1] = zf;
    gemm_lg<1, 256, 264, 2>(sM, Wm2T, wave * 32, lr, quad, acc);
#pragma unroll
    for (int ce = 0; ce < 2; ce++) {
      int n = wave * 32 + ce * 16 + lr;
      float b2 = bm2[n];
#pragma unroll
      for (int r = 0; r < 4; r++) {
        int node = quad * 4 + r;
        size_t idx = (size_t)(n0 + node) * CC + n;
        out[idx] = sH1[node * 132 + n] + acc[0][ce][r] + b2;
      }
    }
  }
}

extern "C" void kernel_launch(void* const* d_in, const int* in_sizes, int n_in,
                              void* d_out, int out_size, void* d_ws, size_t ws_size,
                              hipStream_t stream) {
  const float* x    = (const float*)d_in[0];
  const float* h    = (const float*)d_in[1];
  const int*   ei   = (const int*)d_in[2];
  const float* We1  = (const float*)d_in[3];
  const float* be1  = (const float*)d_in[4];
  const float* We2  = (const float*)d_in[5];
  const float* be2  = (const float*)d_in[6];
  const float* Wn1  = (const float*)d_in[7];
  const float* bn1  = (const float*)d_in[8];
  const float* Wn2  = (const float*)d_in[9];
  const float* bn2  = (const float*)d_in[10];
  const float* Wm1  = (const float*)d_in[11];
  const float* bm1  = (const float*)d_in[12];
  const float* Wm2  = (const float*)d_in[13];
  const float* bm2  = (const float*)d_in[14];
  const float* g1   = (const float*)d_in[15];
  const float* bt1  = (const float*)d_in[16];
  const float* g2   = (const float*)d_in[17];
  const float* bt2  = (const float*)d_in[18];
  float* out = (float*)d_out;

  char* wp = (char*)d_ws;
  size_t off = 0;
  auto alloc = [&](size_t bytes) -> void* {
    void* p = wp + off;
    off = (off + bytes + 255) & ~(size_t)255;
    return p;
  };

  bf16_t* hn16   = (bf16_t*)alloc((size_t)NN * CC * 2);
  bf16_t* PQ     = (bf16_t*)alloc((size_t)NN * 512 * 2);
  float*  sums   = (float*)alloc((size_t)NN * HH * 4);
  int*    cnt    = (int*)alloc((size_t)NN * 4);
  int*    cursor = (int*)alloc((size_t)NN * 4);
  uint4*  edat   = (uint4*)alloc((size_t)(EBLOCKS * ETILE) * 16);
  bf16_t* We1T   = (bf16_t*)alloc(256 * 256 * 2);
  bf16_t* We2T   = (bf16_t*)alloc(256 * 256 * 2);
  bf16_t* Wn1T   = (bf16_t*)alloc(256 * 384 * 2);
  bf16_t* Wn2T   = (bf16_t*)alloc(128 * 256 * 2);
  bf16_t* Wm1T   = (bf16_t*)alloc(256 * 128 * 2);
  bf16_t* Wm2T   = (bf16_t*)alloc(128 * 256 * 2);

  hipMemsetAsync(sums, 0, (size_t)NN * HH * 4, stream);
  hipMemsetAsync(cnt, 0, (size_t)NN * 4, stream);
  hipMemsetAsync(edat + EE, 0, (size_t)(EBLOCKS * ETILE - EE) * 16, stream);  // zero pad edges

  prep_weights<<<1280, 256, 0, stream>>>(We1, We2, Wn1, Wn2, Wm1, Wm2,
                                         We1T, We2T, Wn1T, Wn2T, Wm1T, Wm2T);

  node_pre_kernel<<<(NN + 63) / 64, 256, 0, stream>>>(h, g1, bt1, We1T, be1, hn16, PQ);

  count_kernel<<<EE / 256, 256, 0, stream>>>(ei, cnt);
  scan_kernel<<<1, 1024, 0, stream>>>(cnt, cursor);
  scatter_kernel<<<EE / 256, 256, 0, stream>>>(ei, x, cursor, edat);

  edge_mlp_kernel<<<EBLOCKS, 256, 0, stream>>>(edat, PQ, We1 + 256 * 256,
                                               We2T, be2, sums);

  node_fused_kernel<<<NN / 16, 256, 0, stream>>>(h, hn16, sums, cnt,
                                                 Wn1T, bn1, Wn2T, bn2,
                                                 g2, bt2, Wm1T, bm1, Wm2T, bm2, out);
}

// Round 5
// 310.986 us; speedup vs baseline: 1.6159x; 1.0022x over previous
//
#include <hip/hip_runtime.h>

#define NN 10000
#define CC 128
#define HH 256
#define EE 320000
#define ETILE 64
#define EBLOCKS 5000  // EE/64 exact

typedef __bf16 bf16_t;
typedef __bf16 bf16x8 __attribute__((ext_vector_type(8)));
typedef __bf16 bf16x4 __attribute__((ext_vector_type(4)));
typedef float f32x4 __attribute__((ext_vector_type(4)));

__device__ __forceinline__ float silu_f(float v) {
#if __has_builtin(__builtin_amdgcn_rcpf)
  return v * __builtin_amdgcn_rcpf(1.0f + __expf(-v));
#else
  return v / (1.0f + __expf(-v));
#endif
}

// ---- GEMM slab helper (16x16x32 bf16 MFMA) ----
// Fragment layouts (guide §3, m89-verified):
//   1st operand: lane holds A[m=lane&15][k=quad*8+j]
//   2nd operand: lane holds B[k=quad*8+j][n=lane&15]
//   C/D: col(n)=lane&15, row(m)=quad*4+reg
template<int RE, int KD, int SA, int NT>
__device__ __forceinline__ void gemm_lg(const bf16_t* sAa, const bf16_t* __restrict__ BT,
                                        int nwavebase, int lr, int quad, f32x4 acc[RE][NT]) {
  for (int kk = 0; kk < KD; kk += 32) {
    bf16x8 a[RE]; bf16x8 b[NT];
#pragma unroll
    for (int re = 0; re < RE; re++)
      a[re] = *(const bf16x8*)(sAa + (re * 16 + lr) * SA + kk + quad * 8);
#pragma unroll
    for (int ce = 0; ce < NT; ce++)
      b[ce] = *(const bf16x8*)(BT + (size_t)(nwavebase + ce * 16 + lr) * KD + kk + quad * 8);
#pragma unroll
    for (int re = 0; re < RE; re++)
#pragma unroll
      for (int ce = 0; ce < NT; ce++)
        acc[re][ce] = __builtin_amdgcn_mfma_f32_16x16x32_bf16(a[re], b[ce], acc[re][ce], 0, 0, 0);
  }
}

// ---------- prep: 6 weight transposes + zero sums/cnt (replaces 3 memsets) ----------
__global__ __launch_bounds__(256) void prep_kernel(
    const float* __restrict__ We1, const float* __restrict__ We2,
    const float* __restrict__ Wn1, const float* __restrict__ Wn2,
    const float* __restrict__ Wm1, const float* __restrict__ Wm2,
    bf16_t* __restrict__ We1T, bf16_t* __restrict__ We2T,
    bf16_t* __restrict__ Wn1T, bf16_t* __restrict__ Wn2T,
    bf16_t* __restrict__ Wm1T, bf16_t* __restrict__ Wm2T,
    float* __restrict__ sums, int* __restrict__ cnt) {
  int i = blockIdx.x * 256 + threadIdx.x;
  if (i < 327680) {
    const float* src; bf16_t* dst; int K, Nc, idx;
    if      (i < 65536)  { src = We1; dst = We1T; K = 256; Nc = 256; idx = i; }
    else if (i < 131072) { src = We2; dst = We2T; K = 256; Nc = 256; idx = i - 65536; }
    else if (i < 229376) { src = Wn1; dst = Wn1T; K = 384; Nc = 256; idx = i - 131072; }
    else if (i < 262144) { src = Wn2; dst = Wn2T; K = 256; Nc = 128; idx = i - 229376; }
    else if (i < 294912) { src = Wm1; dst = Wm1T; K = 128; Nc = 256; idx = i - 262144; }
    else                 { src = Wm2; dst = Wm2T; K = 256; Nc = 128; idx = i - 294912; }
    int n = idx / K, k = idx - n * K;
    dst[idx] = (bf16_t)src[(size_t)k * Nc + n];
  } else if (i < 327680 + 640000) {  // NN*HH/4 f32x4 zeros
    f32x4 z = {0.f, 0.f, 0.f, 0.f};
    ((f32x4*)sums)[i - 327680] = z;
  } else if (i < 327680 + 640000 + 2500) {  // NN/4 int4 zeros
    int4 z = {0, 0, 0, 0};
    ((int4*)cnt)[i - 967680] = z;
  }
}

// ---------- fused LN1 + P/Q precompute ----------
// hn = LN(h,g1,bt1) -> hn16
// PQ[n][0:256]   = hn[n] @ We1[0:128,:] + be1   (P, be1 folded)
// PQ[n][256:512] = hn[n] @ We1[128:256,:]       (Q)
__global__ __launch_bounds__(256, 3) void node_pre_kernel(
    const float* __restrict__ h, const float* __restrict__ g1,
    const float* __restrict__ bt1,
    const bf16_t* __restrict__ We1T, const float* __restrict__ be1,
    bf16_t* __restrict__ hn16, bf16_t* __restrict__ PQ) {
  __shared__ __align__(16) float sHf[64 * 132];
  __shared__ __align__(16) bf16_t sHn[64 * 136];
  int tid = threadIdx.x;
  int lane = tid & 63, wave = tid >> 6;
  int lr = lane & 15, quad = lane >> 4;
  int n0 = blockIdx.x * 64;

#pragma unroll
  for (int i = 0; i < 8; i++) {
    int o = tid + i * 256;
    int node = o >> 5, q = o & 31;
    f32x4 v = {0.f, 0.f, 0.f, 0.f};
    if (n0 + node < NN) v = *(const f32x4*)(h + (size_t)(n0 + node) * CC + q * 4);
    *(f32x4*)(sHf + node * 132 + q * 4) = v;
  }
  __syncthreads();

  {
    int node = tid >> 2, c0 = (tid & 3) * 32;
    f32x4 u[8];
    float s = 0.f, sq = 0.f;
#pragma unroll
    for (int j = 0; j < 8; j++) {
      u[j] = *(const f32x4*)(sHf + node * 132 + c0 + j * 4);
#pragma unroll
      for (int r = 0; r < 4; r++) { s += u[j][r]; sq += u[j][r] * u[j][r]; }
    }
    s += __shfl_xor(s, 1); sq += __shfl_xor(sq, 1);
    s += __shfl_xor(s, 2); sq += __shfl_xor(sq, 2);
    float mu = s * (1.0f / CC);
    float var = sq * (1.0f / CC) - mu * mu;
    float rs = rsqrtf(var + 1e-5f);
    bool live = (n0 + node) < NN;
#pragma unroll
    for (int j2 = 0; j2 < 4; j2++) {
      f32x4 gg0 = *(const f32x4*)(g1 + c0 + j2 * 8);
      f32x4 gg1 = *(const f32x4*)(g1 + c0 + j2 * 8 + 4);
      f32x4 bb0 = *(const f32x4*)(bt1 + c0 + j2 * 8);
      f32x4 bb1 = *(const f32x4*)(bt1 + c0 + j2 * 8 + 4);
      bf16x8 ov;
#pragma unroll
      for (int r = 0; r < 4; r++) {
        ov[r] = (bf16_t)((u[j2 * 2][r] - mu) * rs * gg0[r] + bb0[r]);
        ov[r + 4] = (bf16_t)((u[j2 * 2 + 1][r] - mu) * rs * gg1[r] + bb1[r]);
      }
      *(bf16x8*)(sHn + node * 136 + c0 + j2 * 8) = ov;
      if (live) *(bf16x8*)(hn16 + (size_t)(n0 + node) * CC + c0 + j2 * 8) = ov;
    }
  }
  __syncthreads();

  f32x4 zf = {0.f, 0.f, 0.f, 0.f};
#pragma unroll
  for (int p = 0; p < 2; p++) {
    f32x4 acc[4][4];
#pragma unroll
    for (int i = 0; i < 4; i++)
#pragma unroll
      for (int j = 0; j < 4; j++) acc[i][j] = zf;
    for (int kk = 0; kk < 128; kk += 32) {
      bf16x8 a[4]; bf16x8 b[4];
#pragma unroll
      for (int re = 0; re < 4; re++)
        a[re] = *(const bf16x8*)(We1T + (size_t)(wave * 64 + re * 16 + lr) * 256 + p * 128 + kk + quad * 8);
#pragma unroll
      for (int ce = 0; ce < 4; ce++)
        b[ce] = *(const bf16x8*)(sHn + (ce * 16 + lr) * 136 + kk + quad * 8);
#pragma unroll
      for (int re = 0; re < 4; re++)
#pragma unroll
        for (int ce = 0; ce < 4; ce++)
          acc[re][ce] = __builtin_amdgcn_mfma_f32_16x16x32_bf16(a[re], b[ce], acc[re][ce], 0, 0, 0);
    }
#pragma unroll
    for (int re = 0; re < 4; re++) {
      int cbase = wave * 64 + re * 16 + quad * 4;
      f32x4 bb = zf;
      if (p == 0) bb = *(const f32x4*)(be1 + cbase);
#pragma unroll
      for (int ce = 0; ce < 4; ce++) {
        int node = ce * 16 + lr;
        if (n0 + node < NN) {
          bf16x4 o;
#pragma unroll
          for (int r = 0; r < 4; r++) o[r] = (bf16_t)(acc[re][ce][r] + bb[r]);
          *(bf16x4*)(PQ + (size_t)(n0 + node) * 512 + p * 256 + cbase) = o;
        }
      }
    }
  }
}

// ---------- CSR build ----------
__global__ __launch_bounds__(256) void count_kernel(const int* __restrict__ ei, int* __restrict__ cnt) {
  int e = blockIdx.x * 256 + threadIdx.x;
  atomicAdd(&cnt[ei[EE + e]], 1);
}

__global__ __launch_bounds__(1024) void scan_kernel(const int* __restrict__ cnt, int* __restrict__ cursor) {
  __shared__ int wsum[16];
  int tid = threadIdx.x, wave = tid >> 6, lane = tid & 63;
  int base = 0;
  for (int start = 0; start < NN; start += 1024) {
    int i = start + tid;
    int v = (i < NN) ? cnt[i] : 0;
    int s = v;
#pragma unroll
    for (int off = 1; off < 64; off <<= 1) { int t = __shfl_up(s, off); if (lane >= off) s += t; }
    if (lane == 63) wsum[wave] = s;
    __syncthreads();
    if (tid < 16) {
      int ws = wsum[tid];
#pragma unroll
      for (int off = 1; off < 16; off <<= 1) { int t = __shfl_up(ws, off); if (tid >= off) ws += t; }
      wsum[tid] = ws;
    }
    __syncthreads();
    int wp = (wave > 0) ? wsum[wave - 1] : 0;
    if (i < NN) cursor[i] = base + wp + s - v;  // exclusive
    base += wsum[15];
    __syncthreads();
  }
}

__global__ __launch_bounds__(256) void scatter_kernel(const int* __restrict__ ei,
                                                      const float* __restrict__ x,
                                                      int* __restrict__ cursor,
                                                      uint4* __restrict__ edat) {
  int e = blockIdx.x * 256 + threadIdx.x;
  int r = ei[e], c = ei[EE + e];
  float dx = x[3 * r] - x[3 * c];
  float dy = x[3 * r + 1] - x[3 * c + 1];
  float dz = x[3 * r + 2] - x[3 * c + 2];
  float d = sqrtf(dx * dx + dy * dy + dz * dz);
  float cc = (d <= 5.0f) ? 0.5f * (cosf(d * 0.6283185307179586f) + 1.0f) : 0.0f;
  int pos = atomicAdd(&cursor[c], 1);
  uint4 v = {(unsigned)r, (unsigned)c, __float_as_uint(d), __float_as_uint(cc)};
  edat[pos] = v;
}

// ---------- edge kernel: 64-edge tiles, 4 blocks/CU ----------
__global__ __launch_bounds__(256, 4) void edge_mlp_kernel(
    const uint4* __restrict__ edat, const bf16_t* __restrict__ PQ,
    const float* __restrict__ We1last,
    const bf16_t* __restrict__ We2T, const float* __restrict__ be2,
    float* __restrict__ sums) {
  __shared__ __align__(16) bf16_t sM1[ETILE * 264];  // 33792 B
  __shared__ int sRow[ETILE], sCol[ETILE];
  __shared__ float sD[ETILE], sCc[ETILE];
  __shared__ unsigned long long sMask;
  int tid = threadIdx.x;
  int lane = tid & 63, wave = tid >> 6;
  int lr = lane & 15, quad = lane >> 4;
  int e0 = blockIdx.x * ETILE;

  if (tid < ETILE) {
    uint4 v = edat[e0 + tid];
    sRow[tid] = (int)v.x; sCol[tid] = (int)v.y;
    sD[tid] = __uint_as_float(v.z); sCc[tid] = __uint_as_float(v.w);
  }
  __syncthreads();

  if (tid < 64) {
    int fl = (tid > 0) && (sCol[tid] != sCol[tid - 1]);
    unsigned long long m = __ballot(fl);
    if (tid == 0) sMask = m;
  }

  // m1[e][k] = silu(P[row][k] + Q[col][k] + d*wl[k])  (64 edges x 32 8-ch chunks)
#pragma unroll
  for (int i = 0; i < 8; i++) {
    int o = tid + i * 256;
    int e = o >> 5, q = o & 31;
    int k0 = q * 8;
    int row = sRow[e], col = sCol[e];
    float d = sD[e];
    bf16x8 pv = *(const bf16x8*)(PQ + (size_t)row * 512 + k0);
    bf16x8 qv = *(const bf16x8*)(PQ + (size_t)col * 512 + 256 + k0);
    f32x4 wl0 = *(const f32x4*)(We1last + k0);
    f32x4 wl1 = *(const f32x4*)(We1last + k0 + 4);
    bf16x8 m;
#pragma unroll
    for (int j = 0; j < 4; j++) {
      m[j] = (bf16_t)silu_f((float)pv[j] + (float)qv[j] + d * wl0[j]);
      m[j + 4] = (bf16_t)silu_f((float)pv[j + 4] + (float)qv[j + 4] + d * wl1[j]);
    }
    *(bf16x8*)(sM1 + e * 264 + k0) = m;
  }
  __syncthreads();

  // GEMM2: m1 (64 x 256) @ We2 -> wave's 64 channels
  f32x4 zf = {0.f, 0.f, 0.f, 0.f};
  f32x4 acc[4][4];
#pragma unroll
  for (int i = 0; i < 4; i++)
#pragma unroll
    for (int j = 0; j < 4; j++) acc[i][j] = zf;
  gemm_lg<4, 256, 264, 4>(sM1, We2T, wave * 64, lr, quad, acc);

  // in-register epilogue: silu(acc+be2)*cc
  float be2v[4];
#pragma unroll
  for (int ce = 0; ce < 4; ce++) be2v[ce] = be2[wave * 64 + ce * 16 + lr];
#pragma unroll
  for (int re = 0; re < 4; re++) {
    f32x4 cc = *(const f32x4*)(sCc + re * 16 + quad * 4);
#pragma unroll
    for (int ce = 0; ce < 4; ce++)
#pragma unroll
      for (int r = 0; r < 4; r++)
        acc[re][ce][r] = silu_f(acc[re][ce][r] + be2v[ce]) * cc[r];
  }

  // register segmented reduction; wave-uniform segment walk
  {
    unsigned long long w0 = sMask;
    int lo = 0;
    while (lo < ETILE) {
      unsigned long long t = (lo < 63) ? (w0 & (~0ull << (lo + 1))) : 0ull;
      int hi = t ? (__ffsll((long long)t) - 1) : ETILE;
      f32x4 tv = zf;
#pragma unroll
      for (int re = 0; re < 4; re++) {
        int eb = re * 16 + quad * 4;
#pragma unroll
        for (int r = 0; r < 4; r++) {
          int e = eb + r;
          bool in = (e >= lo) && (e < hi);
#pragma unroll
          for (int ce = 0; ce < 4; ce++)
            tv[ce] += in ? acc[re][ce][r] : 0.0f;
        }
      }
#pragma unroll
      for (int ce = 0; ce < 4; ce++) {
        tv[ce] += __shfl_xor(tv[ce], 16);
        tv[ce] += __shfl_xor(tv[ce], 32);
      }
      if (quad == 0) {
        int colv = sCol[lo];
#pragma unroll
        for (int ce = 0; ce < 4; ce++)
          atomicAdd(&sums[(size_t)colv * HH + wave * 64 + ce * 16 + lr], tv[ce]);
      }
      lo = hi;
    }
  }
}

// ---------- fused node pipeline: 64 nodes/block, 157 blocks ----------
__global__ __launch_bounds__(256, 1) void node_fused_kernel(
    const float* __restrict__ h, const bf16_t* __restrict__ hn16,
    const float* __restrict__ sums, const int* __restrict__ cnt,
    const bf16_t* __restrict__ Wn1T, const float* __restrict__ bn1,
    const bf16_t* __restrict__ Wn2T, const float* __restrict__ bn2,
    const float* __restrict__ g2, const float* __restrict__ bt2,
    const bf16_t* __restrict__ Wm1T, const float* __restrict__ bm1,
    const bf16_t* __restrict__ Wm2T, const float* __restrict__ bm2,
    float* __restrict__ out) {
  __shared__ __align__(16) char smem[135168];
  bf16_t* sA1 = (bf16_t*)smem;             // 64x392 bf16 = 50176 B  [hn|m_aggr]
  bf16_t* sM1b = (bf16_t*)(smem + 50176);  // 64x264 bf16 = 33792 B  hidden1
  float*  sH1 = (float*)(smem + 50176);    // 64x132 f32  = 33792 B  (aliases sM1b)
  bf16_t* sLn = (bf16_t*)(smem + 83968);   // 64x136 bf16 = 17408 B  LN2 out
  bf16_t* sH2 = (bf16_t*)(smem + 101376);  // 64x264 bf16 = 33792 B  hidden2
  __shared__ float sRc[64];
  int tid = threadIdx.x;
  int lane = tid & 63, wave = tid >> 6;
  int lr = lane & 15, quad = lane >> 4;
  int n0 = blockIdx.x * 64;  // 157 blocks; last has 16 live nodes

  if (tid < 64) {
    int node = n0 + tid;
    sRc[tid] = (node < NN) ? 1.0f / fmaxf((float)cnt[node], 1.0f) : 0.0f;
  }
  __syncthreads();

  // stage A1 = [hn16 | sums*rc]: 64 nodes x 48 16B-chunks
#pragma unroll
  for (int i = 0; i < 12; i++) {
    int o = tid + i * 256;
    int e = o / 48, q = o - e * 48;
    int node = n0 + e;
    if (q < 16) {
      uint4 v = {0u, 0u, 0u, 0u};
      if (node < NN) v = *(const uint4*)(hn16 + (size_t)node * CC + q * 8);
      *(uint4*)(sA1 + e * 392 + q * 8) = v;
    } else {
      bf16x8 bv = {};
      if (node < NN) {
        float rc = sRc[e];
        const float* sp = sums + (size_t)node * HH + (q - 16) * 8;
#pragma unroll
        for (int k2 = 0; k2 < 8; k2++) bv[k2] = (bf16_t)(sp[k2] * rc);
      }
      *(bf16x8*)(sA1 + e * 392 + 128 + (q - 16) * 8) = bv;
    }
  }
  __syncthreads();

  f32x4 zf = {0.f, 0.f, 0.f, 0.f};
  {  // GEMM1: 64x384 @ 384x256 -> silu -> sM1b
    f32x4 acc[4][4];
#pragma unroll
    for (int i = 0; i < 4; i++)
#pragma unroll
      for (int j = 0; j < 4; j++) acc[i][j] = zf;
    gemm_lg<4, 384, 392, 4>(sA1, Wn1T, wave * 64, lr, quad, acc);
    __syncthreads();  // (sM1b region not yet in use; barrier orders nothing harmful)
#pragma unroll
    for (int ce = 0; ce < 4; ce++) {
      int n = wave * 64 + ce * 16 + lr;
      float b1 = bn1[n];
#pragma unroll
      for (int re = 0; re < 4; re++)
#pragma unroll
        for (int r = 0; r < 4; r++)
          sM1b[(re * 16 + quad * 4 + r) * 264 + n] = (bf16_t)silu_f(acc[re][ce][r] + b1);
    }
  }
  __syncthreads();

  float h1v[4][2][4];
  {  // GEMM2: 64x256 @ 256x128; h1 = h + hn + hd (registers)
    f32x4 acc[4][2];
#pragma unroll
    for (int i = 0; i < 4; i++) { acc[i][0] = zf; acc[i][1] = zf; }
    gemm_lg<4, 256, 264, 2>(sM1b, Wn2T, wave * 32, lr, quad, acc);
#pragma unroll
    for (int ce = 0; ce < 2; ce++) {
      int n = wave * 32 + ce * 16 + lr;
      float b2 = bn2[n];
#pragma unroll
      for (int re = 0; re < 4; re++)
#pragma unroll
        for (int r = 0; r < 4; r++) {
          int node = re * 16 + quad * 4 + r;
          float hv = 0.f;
          if (n0 + node < NN) hv = h[(size_t)(n0 + node) * CC + n];
          h1v[re][ce][r] = hv + (float)sA1[node * 392 + n] + acc[re][ce][r] + b2;
        }
    }
  }
  __syncthreads();  // all reads of sM1b/sA1 done -> safe to alias

  // write h1 to sH1 (aliases sM1b)
#pragma unroll
  for (int ce = 0; ce < 2; ce++) {
    int n = wave * 32 + ce * 16 + lr;
#pragma unroll
    for (int re = 0; re < 4; re++)
#pragma unroll
      for (int r = 0; r < 4; r++)
        sH1[(re * 16 + quad * 4 + r) * 132 + n] = h1v[re][ce][r];
  }
  __syncthreads();

  {  // LN2 in-LDS: thread -> node tid>>2, channels (tid&3)*32..+31
    int node = tid >> 2, c0 = (tid & 3) * 32;
    f32x4 u[8];
    float s = 0.f, sq = 0.f;
#pragma unroll
    for (int j = 0; j < 8; j++) {
      u[j] = *(const f32x4*)(sH1 + node * 132 + c0 + j * 4);
#pragma unroll
      for (int r = 0; r < 4; r++) { s += u[j][r]; sq += u[j][r] * u[j][r]; }
    }
    s += __shfl_xor(s, 1); sq += __shfl_xor(sq, 1);
    s += __shfl_xor(s, 2); sq += __shfl_xor(sq, 2);
    float mu = s * (1.0f / CC);
    float var = sq * (1.0f / CC) - mu * mu;
    float rs = rsqrtf(var + 1e-5f);
#pragma unroll
    for (int j2 = 0; j2 < 4; j2++) {
      f32x4 gg0 = *(const f32x4*)(g2 + c0 + j2 * 8);
      f32x4 gg1 = *(const f32x4*)(g2 + c0 + j2 * 8 + 4);
      f32x4 bb0 = *(const f32x4*)(bt2 + c0 + j2 * 8);
      f32x4 bb1 = *(const f32x4*)(bt2 + c0 + j2 * 8 + 4);
      bf16x8 ov;
#pragma unroll
      for (int r = 0; r < 4; r++) {
        ov[r] = (bf16_t)((u[j2 * 2][r] - mu) * rs * gg0[r] + bb0[r]);
        ov[r + 4] = (bf16_t)((u[j2 * 2 + 1][r] - mu) * rs * gg1[r] + bb1[r]);
      }
      *(bf16x8*)(sLn + node * 136 + c0 + j2 * 8) = ov;
    }
  }
  __syncthreads();

  {  // GEMM3: 64x128 @ 128x256 -> silu -> sH2
    f32x4 acc[4][4];
#pragma unroll
    for (int i = 0; i < 4; i++)
#pragma unroll
      for (int j = 0; j < 4; j++) acc[i][j] = zf;
    gemm_lg<4, 128, 136, 4>(sLn, Wm1T, wave * 64, lr, quad, acc);
#pragma unroll
    for (int ce = 0; ce < 4; ce++) {
      int n = wave * 64 + ce * 16 + lr;
      float b1 = bm1[n];
#pragma unroll
      for (int re = 0; re < 4; re++)
#pragma unroll
        for (int r = 0; r < 4; r++)
          sH2[(re * 16 + quad * 4 + r) * 264 + n] = (bf16_t)silu_f(acc[re][ce][r] + b1);
    }
  }
  __syncthreads();

  {  // GEMM4: 64x256 @ 256x128; out = h1 + hd2
    f32x4 acc[4][2];
#pragma unroll
    for (int i = 0; i < 4; i++) { acc[i][0] = zf; acc[i][1] = zf; }
    gemm_lg<4, 256, 264, 2>(sH2, Wm2T, wave * 32, lr, quad, acc);
#pragma unroll
    for (int ce = 0; ce < 2; ce++) {
      int n = wave * 32 + ce * 16 + lr;
      float b2 = bm2[n];
#pragma unroll
      for (int re = 0; re < 4; re++)
#pragma unroll
        for (int r = 0; r < 4; r++) {
          int node = re * 16 + quad * 4 + r;
          if (n0 + node < NN)
            out[(size_t)(n0 + node) * CC + n] = sH1[node * 132 + n] + acc[re][ce][r] + b2;
        }
    }
  }
}

extern "C" void kernel_launch(void* const* d_in, const int* in_sizes, int n_in,
                              void* d_out, int out_size, void* d_ws, size_t ws_size,
                              hipStream_t stream) {
  const float* x    = (const float*)d_in[0];
  const float* h    = (const float*)d_in[1];
  const int*   ei   = (const int*)d_in[2];
  const float* We1  = (const float*)d_in[3];
  const float* be1  = (const float*)d_in[4];
  const float* We2  = (const float*)d_in[5];
  const float* be2  = (const float*)d_in[6];
  const float* Wn1  = (const float*)d_in[7];
  const float* bn1  = (const float*)d_in[8];
  const float* Wn2  = (const float*)d_in[9];
  const float* bn2  = (const float*)d_in[10];
  const float* Wm1  = (const float*)d_in[11];
  const float* bm1  = (const float*)d_in[12];
  const float* Wm2  = (const float*)d_in[13];
  const float* bm2  = (const float*)d_in[14];
  const float* g1   = (const float*)d_in[15];
  const float* bt1  = (const float*)d_in[16];
  const float* g2   = (const float*)d_in[17];
  const float* bt2  = (const float*)d_in[18];
  float* out = (float*)d_out;

  char* wp = (char*)d_ws;
  size_t off = 0;
  auto alloc = [&](size_t bytes) -> void* {
    void* p = wp + off;
    off = (off + bytes + 255) & ~(size_t)255;
    return p;
  };

  bf16_t* hn16   = (bf16_t*)alloc((size_t)NN * CC * 2);
  bf16_t* PQ     = (bf16_t*)alloc((size_t)NN * 512 * 2);
  float*  sums   = (float*)alloc((size_t)NN * HH * 4);
  int*    cnt    = (int*)alloc((size_t)NN * 4);
  int*    cursor = (int*)alloc((size_t)NN * 4);
  uint4*  edat   = (uint4*)alloc((size_t)EE * 16);
  bf16_t* We1T   = (bf16_t*)alloc(256 * 256 * 2);
  bf16_t* We2T   = (bf16_t*)alloc(256 * 256 * 2);
  bf16_t* Wn1T   = (bf16_t*)alloc(256 * 384 * 2);
  bf16_t* Wn2T   = (bf16_t*)alloc(128 * 256 * 2);
  bf16_t* Wm1T   = (bf16_t*)alloc(256 * 128 * 2);
  bf16_t* Wm2T   = (bf16_t*)alloc(128 * 256 * 2);

  prep_kernel<<<3790, 256, 0, stream>>>(We1, We2, Wn1, Wn2, Wm1, Wm2,
                                        We1T, We2T, Wn1T, Wn2T, Wm1T, Wm2T,
                                        sums, cnt);

  node_pre_kernel<<<(NN + 63) / 64, 256, 0, stream>>>(h, g1, bt1, We1T, be1, hn16, PQ);

  count_kernel<<<EE / 256, 256, 0, stream>>>(ei, cnt);
  scan_kernel<<<1, 1024, 0, stream>>>(cnt, cursor);
  scatter_kernel<<<EE / 256, 256, 0, stream>>>(ei, x, cursor, edat);

  edge_mlp_kernel<<<EBLOCKS, 256, 0, stream>>>(edat, PQ, We1 + 256 * 256,
                                               We2T, be2, sums);

  node_fused_kernel<<<(NN + 63) / 64, 256, 0, stream>>>(h, hn16, sums, cnt,
                                                        Wn1T, bn1, Wn2T, bn2,
                                                        g2, bt2, Wm1T, bm1, Wm2T, bm2, out);
}

// Round 7
// 294.895 us; speedup vs baseline: 1.7041x; 1.0546x over previous
//
#include <hip/hip_runtime.h>

#define NN 10000
#define CC 128
#define HH 256
#define EE 320000
#define ETILE 96
#define EBLOCKS 3334  // ceil(EE/96); pad = 64 zero-edges

typedef __bf16 bf16_t;
typedef __bf16 bf16x8 __attribute__((ext_vector_type(8)));
typedef __bf16 bf16x4 __attribute__((ext_vector_type(4)));
typedef float f32x4 __attribute__((ext_vector_type(4)));

__device__ __forceinline__ float silu_f(float v) {
#if __has_builtin(__builtin_amdgcn_rcpf)
  return v * __builtin_amdgcn_rcpf(1.0f + __expf(-v));
#else
  return v / (1.0f + __expf(-v));
#endif
}

// ---- GEMM slab helper (16x16x32 bf16 MFMA) ----
// Fragment layouts (guide §3, m89-verified):
//   1st operand: lane holds A[m=lane&15][k=quad*8+j]
//   2nd operand: lane holds B[k=quad*8+j][n=lane&15]
//   C/D: col(n)=lane&15, row(m)=quad*4+reg
template<int RE, int KD, int SA, int NT>
__device__ __forceinline__ void gemm_lg(const bf16_t* sAa, const bf16_t* __restrict__ BT,
                                        int nwavebase, int lr, int quad, f32x4 acc[RE][NT]) {
  for (int kk = 0; kk < KD; kk += 32) {
    bf16x8 a[RE]; bf16x8 b[NT];
#pragma unroll
    for (int re = 0; re < RE; re++)
      a[re] = *(const bf16x8*)(sAa + (re * 16 + lr) * SA + kk + quad * 8);
#pragma unroll
    for (int ce = 0; ce < NT; ce++)
      b[ce] = *(const bf16x8*)(BT + (size_t)(nwavebase + ce * 16 + lr) * KD + kk + quad * 8);
#pragma unroll
    for (int re = 0; re < RE; re++)
#pragma unroll
      for (int ce = 0; ce < NT; ce++)
        acc[re][ce] = __builtin_amdgcn_mfma_f32_16x16x32_bf16(a[re], b[ce], acc[re][ce], 0, 0, 0);
  }
}

// ---------- prep: 6 weight transposes + zero sums/cnt/edat-pad ----------
__global__ __launch_bounds__(256) void prep_kernel(
    const float* __restrict__ We1, const float* __restrict__ We2,
    const float* __restrict__ Wn1, const float* __restrict__ Wn2,
    const float* __restrict__ Wm1, const float* __restrict__ Wm2,
    bf16_t* __restrict__ We1T, bf16_t* __restrict__ We2T,
    bf16_t* __restrict__ Wn1T, bf16_t* __restrict__ Wn2T,
    bf16_t* __restrict__ Wm1T, bf16_t* __restrict__ Wm2T,
    float* __restrict__ sums, int* __restrict__ cnt, uint4* __restrict__ edat) {
  int i = blockIdx.x * 256 + threadIdx.x;
  if (i < 327680) {
    const float* src; bf16_t* dst; int K, Nc, idx;
    if      (i < 65536)  { src = We1; dst = We1T; K = 256; Nc = 256; idx = i; }
    else if (i < 131072) { src = We2; dst = We2T; K = 256; Nc = 256; idx = i - 65536; }
    else if (i < 229376) { src = Wn1; dst = Wn1T; K = 384; Nc = 256; idx = i - 131072; }
    else if (i < 262144) { src = Wn2; dst = Wn2T; K = 256; Nc = 128; idx = i - 229376; }
    else if (i < 294912) { src = Wm1; dst = Wm1T; K = 128; Nc = 256; idx = i - 262144; }
    else                 { src = Wm2; dst = Wm2T; K = 256; Nc = 128; idx = i - 294912; }
    int n = idx / K, k = idx - n * K;
    dst[idx] = (bf16_t)src[(size_t)k * Nc + n];
  } else if (i < 327680 + 640000) {  // NN*HH/4 f32x4 zeros
    f32x4 z = {0.f, 0.f, 0.f, 0.f};
    ((f32x4*)sums)[i - 327680] = z;
  } else if (i < 327680 + 640000 + 2500) {  // NN/4 int4 zeros
    int4 z = {0, 0, 0, 0};
    ((int4*)cnt)[i - 967680] = z;
  } else if (i < 327680 + 640000 + 2500 + 64) {  // zero pad edges
    uint4 z = {0u, 0u, 0u, 0u};
    edat[EE + (i - 970180)] = z;
  }
}

// ---------- fused LN1 + P/Q precompute, 16 nodes/block, 625 blocks ----------
// hn = LN(h,g1,bt1) -> hn16
// PQ[n][0:256]   = hn[n] @ We1[0:128,:] + be1   (P, be1 folded)
// PQ[n][256:512] = hn[n] @ We1[128:256,:]       (Q)
__global__ __launch_bounds__(256, 4) void node_pre_kernel(
    const float* __restrict__ h, const float* __restrict__ g1,
    const float* __restrict__ bt1,
    const bf16_t* __restrict__ We1T, const float* __restrict__ be1,
    bf16_t* __restrict__ hn16, bf16_t* __restrict__ PQ) {
  __shared__ __align__(16) bf16_t sHn[16 * 136];
  int tid = threadIdx.x;
  int lane = tid & 63, wave = tid >> 6;
  int lr = lane & 15, quad = lane >> 4;
  int n0 = blockIdx.x * 16;  // 625 * 16 = NN exact

  // LN1: 16 threads/node, 8 channels each
  {
    int node = tid >> 4, c0 = (tid & 15) * 8;
    size_t base = (size_t)(n0 + node) * CC;
    f32x4 u0 = *(const f32x4*)(h + base + c0);
    f32x4 u1 = *(const f32x4*)(h + base + c0 + 4);
    float s = 0.f, sq = 0.f;
#pragma unroll
    for (int j = 0; j < 4; j++) { s += u0[j] + u1[j]; sq += u0[j] * u0[j] + u1[j] * u1[j]; }
#pragma unroll
    for (int o = 8; o > 0; o >>= 1) { s += __shfl_xor(s, o); sq += __shfl_xor(sq, o); }
    float mu = s * (1.0f / CC);
    float var = sq * (1.0f / CC) - mu * mu;
    float rs = rsqrtf(var + 1e-5f);
    f32x4 gg0 = *(const f32x4*)(g1 + c0), gg1 = *(const f32x4*)(g1 + c0 + 4);
    f32x4 bb0 = *(const f32x4*)(bt1 + c0), bb1 = *(const f32x4*)(bt1 + c0 + 4);
    bf16x8 ov;
#pragma unroll
    for (int j = 0; j < 4; j++) {
      ov[j] = (bf16_t)((u0[j] - mu) * rs * gg0[j] + bb0[j]);
      ov[j + 4] = (bf16_t)((u1[j] - mu) * rs * gg1[j] + bb1[j]);
    }
    *(bf16x8*)(sHn + node * 136 + c0) = ov;
    *(bf16x8*)(hn16 + base + c0) = ov;
  }
  __syncthreads();

  // PQ GEMM: waves 0-1 -> P (We1T k-cols 0:128), waves 2-3 -> Q (k-cols 128:256).
  // Each wave: 128 out-channels = 8 m-tiles, 1 n-tile (16 nodes).
  bool isQ = wave >= 2;
  int rbase = (wave & 1) * 128;
  int koff = isQ ? 128 : 0;
  f32x4 zf = {0.f, 0.f, 0.f, 0.f};
  f32x4 acc[8];
#pragma unroll
  for (int i = 0; i < 8; i++) acc[i] = zf;
  for (int kk = 0; kk < 128; kk += 32) {
    bf16x8 b = *(const bf16x8*)(sHn + lr * 136 + kk + quad * 8);
    bf16x8 a[8];
#pragma unroll
    for (int re = 0; re < 8; re++)
      a[re] = *(const bf16x8*)(We1T + (size_t)(rbase + re * 16 + lr) * 256 + koff + kk + quad * 8);
#pragma unroll
    for (int re = 0; re < 8; re++)
      acc[re] = __builtin_amdgcn_mfma_f32_16x16x32_bf16(a[re], b, acc[re], 0, 0, 0);
  }
  // C: col = node (lr), row = channel rbase + re*16 + quad*4 + r
#pragma unroll
  for (int re = 0; re < 8; re++) {
    int cb = rbase + re * 16 + quad * 4;
    f32x4 bb = isQ ? zf : *(const f32x4*)(be1 + cb);
    bf16x4 o;
#pragma unroll
    for (int r = 0; r < 4; r++) o[r] = (bf16_t)(acc[re][r] + bb[r]);
    *(bf16x4*)(PQ + (size_t)(n0 + lr) * 512 + (isQ ? 256 : 0) + cb) = o;
  }
}

// ---------- CSR build ----------
__global__ __launch_bounds__(256) void count_kernel(const int* __restrict__ ei, int* __restrict__ cnt) {
  int e = blockIdx.x * 256 + threadIdx.x;
  atomicAdd(&cnt[ei[EE + e]], 1);
}

// single-pass scan: thread owns 10 contiguous elements
__global__ __launch_bounds__(1024) void scan_kernel(const int* __restrict__ cnt, int* __restrict__ cursor) {
  __shared__ int wsum[16];
  int tid = threadIdx.x, wave = tid >> 6, lane = tid & 63;
  int base = tid * 10;
  int v[10]; int S = 0;
#pragma unroll
  for (int j = 0; j < 10; j++) {
    int i = base + j;
    v[j] = (i < NN) ? cnt[i] : 0;
    S += v[j];
  }
  int s = S;
#pragma unroll
  for (int off = 1; off < 64; off <<= 1) { int t = __shfl_up(s, off); if (lane >= off) s += t; }
  if (lane == 63) wsum[wave] = s;
  __syncthreads();
  if (tid < 16) {
    int ws = wsum[tid];
#pragma unroll
    for (int off = 1; off < 16; off <<= 1) { int t = __shfl_up(ws, off); if (tid >= off) ws += t; }
    wsum[tid] = ws;
  }
  __syncthreads();
  int ex = ((wave > 0) ? wsum[wave - 1] : 0) + s - S;  // exclusive prefix of this chunk
#pragma unroll
  for (int j = 0; j < 10; j++) {
    int i = base + j;
    if (i < NN) cursor[i] = ex;
    ex += v[j];
  }
}

__global__ __launch_bounds__(256) void scatter_kernel(const int* __restrict__ ei,
                                                      const float* __restrict__ x,
                                                      int* __restrict__ cursor,
                                                      uint4* __restrict__ edat) {
  int e = blockIdx.x * 256 + threadIdx.x;
  int r = ei[e], c = ei[EE + e];
  float dx = x[3 * r] - x[3 * c];
  float dy = x[3 * r + 1] - x[3 * c + 1];
  float dz = x[3 * r + 2] - x[3 * c + 2];
  float d = sqrtf(dx * dx + dy * dy + dz * dz);
  float cc = (d <= 5.0f) ? 0.5f * (cosf(d * 0.6283185307179586f) + 1.0f) : 0.0f;
  int pos = atomicAdd(&cursor[c], 1);
  uint4 v = {(unsigned)r, (unsigned)c, __float_as_uint(d), __float_as_uint(cc)};
  edat[pos] = v;
}

// ---------- edge kernel: 96-edge tiles, 3 blocks/CU, tile-skip reduction ----------
__global__ __launch_bounds__(256, 3) void edge_mlp_kernel(
    const uint4* __restrict__ edat, const bf16_t* __restrict__ PQ,
    const float* __restrict__ We1last,
    const bf16_t* __restrict__ We2T, const float* __restrict__ be2,
    float* __restrict__ sums) {
  __shared__ __align__(16) bf16_t sM1[ETILE * 264];  // 50688 B
  __shared__ int sRow[ETILE], sCol[ETILE];
  __shared__ float sD[ETILE], sCc[ETILE];
  __shared__ unsigned long long sMaskA;
  __shared__ unsigned sMaskB;
  int tid = threadIdx.x;
  int lane = tid & 63, wave = tid >> 6;
  int lr = lane & 15, quad = lane >> 4;
  int e0 = blockIdx.x * ETILE;

  if (tid < ETILE) {
    uint4 v = edat[e0 + tid];
    sRow[tid] = (int)v.x; sCol[tid] = (int)v.y;
    sD[tid] = __uint_as_float(v.z); sCc[tid] = __uint_as_float(v.w);
  }
  __syncthreads();

  if (tid < ETILE) {
    int fl = (tid > 0) && (sCol[tid] != sCol[tid - 1]);
    unsigned long long m = __ballot(fl);
    if (tid == 0) sMaskA = m;
    if (tid == 64) sMaskB = (unsigned)m;
  }

  // m1[e][k] = silu(P[row][k] + Q[col][k] + d*wl[k])  (96 edges x 32 8-ch chunks)
#pragma unroll
  for (int i = 0; i < ETILE * 32 / 256; i++) {  // 12
    int o = tid + i * 256;
    int e = o >> 5, q = o & 31;
    int k0 = q * 8;
    int row = sRow[e], col = sCol[e];
    float d = sD[e];
    bf16x8 pv = *(const bf16x8*)(PQ + (size_t)row * 512 + k0);
    bf16x8 qv = *(const bf16x8*)(PQ + (size_t)col * 512 + 256 + k0);
    f32x4 wl0 = *(const f32x4*)(We1last + k0);
    f32x4 wl1 = *(const f32x4*)(We1last + k0 + 4);
    bf16x8 m;
#pragma unroll
    for (int j = 0; j < 4; j++) {
      m[j] = (bf16_t)silu_f((float)pv[j] + (float)qv[j] + d * wl0[j]);
      m[j + 4] = (bf16_t)silu_f((float)pv[j + 4] + (float)qv[j + 4] + d * wl1[j]);
    }
    *(bf16x8*)(sM1 + e * 264 + k0) = m;
  }
  __syncthreads();

  // GEMM2: m1 (96 x 256) @ We2 -> wave's 64 channels
  f32x4 zf = {0.f, 0.f, 0.f, 0.f};
  f32x4 acc[6][4];
#pragma unroll
  for (int i = 0; i < 6; i++)
#pragma unroll
    for (int j = 0; j < 4; j++) acc[i][j] = zf;
  gemm_lg<6, 256, 264, 4>(sM1, We2T, wave * 64, lr, quad, acc);

  // in-register epilogue: silu(acc+be2)*cc  (edge e = re*16+quad*4+r)
  float be2v[4];
#pragma unroll
  for (int ce = 0; ce < 4; ce++) be2v[ce] = be2[wave * 64 + ce * 16 + lr];
#pragma unroll
  for (int re = 0; re < 6; re++) {
    f32x4 cc = *(const f32x4*)(sCc + re * 16 + quad * 4);
#pragma unroll
    for (int ce = 0; ce < 4; ce++)
#pragma unroll
      for (int r = 0; r < 4; r++)
        acc[re][ce][r] = silu_f(acc[re][ce][r] + be2v[ce]) * cc[r];
  }

  // register segmented reduction with static tile-skip (wave-uniform branches).
  // All mask arithmetic in 64-bit: shift amounts stay < 64 (lo<=95 -> lo-63<=32,
  // well-defined for ull; at 32 it zeroes all of mB's 32 bits -> hi=ETILE).
  {
    unsigned long long mA = sMaskA;
    unsigned long long mB = (unsigned long long)sMaskB;  // bit i = edge 64+i
    int lo = 0;
    while (lo < ETILE) {
      int hi;
      if (lo < 63) {
        unsigned long long t = mA & (~0ull << (lo + 1));
        hi = t ? (__ffsll((long long)t) - 1)
               : (mB ? 64 + __ffsll((long long)mB) - 1 : ETILE);
      } else {
        unsigned long long t1 = mB & (~0ull << (lo - 63));
        hi = t1 ? 64 + __ffsll((long long)t1) - 1 : ETILE;
      }
      f32x4 tv = zf;
#pragma unroll
      for (int re = 0; re < 6; re++) {
        int t0 = re * 16, t1e = t0 + 16;
        if (t1e <= lo || t0 >= hi) continue;  // tile outside segment (scalar skip)
        if (t0 >= lo && t1e <= hi) {          // tile fully inside: unmasked adds
#pragma unroll
          for (int r = 0; r < 4; r++)
#pragma unroll
            for (int ce = 0; ce < 4; ce++)
              tv[ce] += acc[re][ce][r];
        } else {                              // straddles boundary: masked adds
          int eb = t0 + quad * 4;
#pragma unroll
          for (int r = 0; r < 4; r++) {
            int e = eb + r;
            bool in = (e >= lo) && (e < hi);
#pragma unroll
            for (int ce = 0; ce < 4; ce++)
              tv[ce] += in ? acc[re][ce][r] : 0.0f;
          }
        }
      }
#pragma unroll
      for (int ce = 0; ce < 4; ce++) {
        tv[ce] += __shfl_xor(tv[ce], 16);
        tv[ce] += __shfl_xor(tv[ce], 32);
      }
      if (quad == 0) {
        int colv = sCol[lo];
#pragma unroll
        for (int ce = 0; ce < 4; ce++)
          atomicAdd(&sums[(size_t)colv * HH + wave * 64 + ce * 16 + lr], tv[ce]);
      }
      lo = hi;
    }
  }
}

// ---------- fused node pipeline: 16 nodes/block, 625 blocks ----------
__global__ __launch_bounds__(256, 3) void node_fused_kernel(
    const float* __restrict__ h, const bf16_t* __restrict__ hn16,
    const float* __restrict__ sums, const int* __restrict__ cnt,
    const bf16_t* __restrict__ Wn1T, const float* __restrict__ bn1,
    const bf16_t* __restrict__ Wn2T, const float* __restrict__ bn2,
    const float* __restrict__ g2, const float* __restrict__ bt2,
    const bf16_t* __restrict__ Wm1T, const float* __restrict__ bm1,
    const bf16_t* __restrict__ Wm2T, const float* __restrict__ bm2,
    float* __restrict__ out) {
  __shared__ __align__(16) bf16_t sA1[16 * 392];
  __shared__ __align__(16) bf16_t sM[16 * 264];
  __shared__ __align__(16) float sH1[16 * 132];
  __shared__ __align__(16) bf16_t sLn[16 * 136];
  __shared__ float sRc[16];
  int tid = threadIdx.x;
  int lane = tid & 63, wave = tid >> 6;
  int lr = lane & 15, quad = lane >> 4;
  int n0 = blockIdx.x * 16;  // exact

  if (tid < 16) sRc[tid] = 1.0f / fmaxf((float)cnt[n0 + tid], 1.0f);
  __syncthreads();

  // stage A1 = [hn16 | sums*rc]: 16 nodes x 48 16B-chunks
#pragma unroll
  for (int i = 0; i < 3; i++) {
    int o = tid + i * 256;
    int e = o / 48, q = o - e * 48;
    int node = n0 + e;
    if (q < 16) {
      *(uint4*)(sA1 + e * 392 + q * 8) = *(const uint4*)(hn16 + (size_t)node * CC + q * 8);
    } else {
      float rc = sRc[e];
      const float* sp = sums + (size_t)node * HH + (q - 16) * 8;
      bf16x8 bv;
#pragma unroll
      for (int k2 = 0; k2 < 8; k2++) bv[k2] = (bf16_t)(sp[k2] * rc);
      *(bf16x8*)(sA1 + e * 392 + 128 + (q - 16) * 8) = bv;
    }
  }
  __syncthreads();

  f32x4 zf = {0.f, 0.f, 0.f, 0.f};
  {  // GEMM1: 16x384 @ 384x256 -> silu -> sM
    f32x4 acc[1][4];
#pragma unroll
    for (int j = 0; j < 4; j++) acc[0][j] = zf;
    gemm_lg<1, 384, 392, 4>(sA1, Wn1T, wave * 64, lr, quad, acc);
#pragma unroll
    for (int ce = 0; ce < 4; ce++) {
      int n = wave * 64 + ce * 16 + lr;
      float b1 = bn1[n];
#pragma unroll
      for (int r = 0; r < 4; r++)
        sM[(quad * 4 + r) * 264 + n] = (bf16_t)silu_f(acc[0][ce][r] + b1);
    }
  }
  __syncthreads();

  {  // GEMM2: 16x256 @ 256x128; h1 = h + hn + hd -> sH1
    f32x4 acc[1][2];
    acc[0][0] = zf; acc[0][1] = zf;
    gemm_lg<1, 256, 264, 2>(sM, Wn2T, wave * 32, lr, quad, acc);
#pragma unroll
    for (int ce = 0; ce < 2; ce++) {
      int n = wave * 32 + ce * 16 + lr;
      float b2 = bn2[n];
#pragma unroll
      for (int r = 0; r < 4; r++) {
        int node = quad * 4 + r;
        size_t idx = (size_t)(n0 + node) * CC + n;
        float hn_v = (float)sA1[node * 392 + n];
        sH1[node * 132 + n] = h[idx] + hn_v + acc[0][ce][r] + b2;
      }
    }
  }
  __syncthreads();

  {  // LN2 in-LDS: thread -> node tid>>4, channels (tid&15)*8..+7
    int node = tid >> 4, c0 = (tid & 15) * 8;
    f32x4 u0 = *(const f32x4*)(sH1 + node * 132 + c0);
    f32x4 u1 = *(const f32x4*)(sH1 + node * 132 + c0 + 4);
    float s = 0.f, sq = 0.f;
#pragma unroll
    for (int j = 0; j < 4; j++) { s += u0[j] + u1[j]; sq += u0[j] * u0[j] + u1[j] * u1[j]; }
#pragma unroll
    for (int o = 8; o > 0; o >>= 1) { s += __shfl_xor(s, o); sq += __shfl_xor(sq, o); }
    float mu = s * (1.0f / CC);
    float var = sq * (1.0f / CC) - mu * mu;
    float rs = rsqrtf(var + 1e-5f);
    f32x4 gg0 = *(const f32x4*)(g2 + c0), gg1 = *(const f32x4*)(g2 + c0 + 4);
    f32x4 bb0 = *(const f32x4*)(bt2 + c0), bb1 = *(const f32x4*)(bt2 + c0 + 4);
    bf16x8 ov;
#pragma unroll
    for (int j = 0; j < 4; j++) {
      ov[j] = (bf16_t)((u0[j] - mu) * rs * gg0[j] + bb0[j]);
      ov[j + 4] = (bf16_t)((u1[j] - mu) * rs * gg1[j] + bb1[j]);
    }
    *(bf16x8*)(sLn + node * 136 + c0) = ov;
  }
  __syncthreads();

  {  // GEMM3: 16x128 @ 128x256 -> silu -> sM (reuse)
    f32x4 acc[1][4];
#pragma unroll
    for (int j = 0; j < 4; j++) acc[0][j] = zf;
    gemm_lg<1, 128, 136, 4>(sLn, Wm1T, wave * 64, lr, quad, acc);
#pragma unroll
    for (int ce = 0; ce < 4; ce++) {
      int n = wave * 64 + ce * 16 + lr;
      float b1 = bm1[n];
#pragma unroll
      for (int r = 0; r < 4; r++)
        sM[(quad * 4 + r) * 264 + n] = (bf16_t)silu_f(acc[0][ce][r] + b1);
    }
  }
  __syncthreads();

  {  // GEMM4: 16x256 @ 256x128; out = h1 + hd2
    f32x4 acc[1][2];
    acc[0][0] = zf; acc[0][1] = zf;
    gemm_lg<1, 256, 264, 2>(sM, Wm2T, wave * 32, lr, quad, acc);
#pragma unroll
    for (int ce = 0; ce < 2; ce++) {
      int n = wave * 32 + ce * 16 + lr;
      float b2 = bm2[n];
#pragma unroll
      for (int r = 0; r < 4; r++) {
        int node = quad * 4 + r;
        size_t idx = (size_t)(n0 + node) * CC + n;
        out[idx] = sH1[node * 132 + n] + acc[0][ce][r] + b2;
      }
    }
  }
}

extern "C" void kernel_launch(void* const* d_in, const int* in_sizes, int n_in,
                              void* d_out, int out_size, void* d_ws, size_t ws_size,
                              hipStream_t stream) {
  const float* x    = (const float*)d_in[0];
  const float* h    = (const float*)d_in[1];
  const int*   ei   = (const int*)d_in[2];
  const float* We1  = (const float*)d_in[3];
  const float* be1  = (const float*)d_in[4];
  const float* We2  = (const float*)d_in[5];
  const float* be2  = (const float*)d_in[6];
  const float* Wn1  = (const float*)d_in[7];
  const float* bn1  = (const float*)d_in[8];
  const float* Wn2  = (const float*)d_in[9];
  const float* bn2  = (const float*)d_in[10];
  const float* Wm1  = (const float*)d_in[11];
  const float* bm1  = (const float*)d_in[12];
  const float* Wm2  = (const float*)d_in[13];
  const float* bm2  = (const float*)d_in[14];
  const float* g1   = (const float*)d_in[15];
  const float* bt1  = (const float*)d_in[16];
  const float* g2   = (const float*)d_in[17];
  const float* bt2  = (const float*)d_in[18];
  float* out = (float*)d_out;

  char* wp = (char*)d_ws;
  size_t off = 0;
  auto alloc = [&](size_t bytes) -> void* {
    void* p = wp + off;
    off = (off + bytes + 255) & ~(size_t)255;
    return p;
  };

  bf16_t* hn16   = (bf16_t*)alloc((size_t)NN * CC * 2);
  bf16_t* PQ     = (bf16_t*)alloc((size_t)NN * 512 * 2);
  float*  sums   = (float*)alloc((size_t)NN * HH * 4);
  int*    cnt    = (int*)alloc((size_t)NN * 4);
  int*    cursor = (int*)alloc((size_t)NN * 4);
  uint4*  edat   = (uint4*)alloc((size_t)(EBLOCKS * ETILE) * 16);
  bf16_t* We1T   = (bf16_t*)alloc(256 * 256 * 2);
  bf16_t* We2T   = (bf16_t*)alloc(256 * 256 * 2);
  bf16_t* Wn1T   = (bf16_t*)alloc(256 * 384 * 2);
  bf16_t* Wn2T   = (bf16_t*)alloc(128 * 256 * 2);
  bf16_t* Wm1T   = (bf16_t*)alloc(256 * 128 * 2);
  bf16_t* Wm2T   = (bf16_t*)alloc(128 * 256 * 2);

  prep_kernel<<<3791, 256, 0, stream>>>(We1, We2, Wn1, Wn2, Wm1, Wm2,
                                        We1T, We2T, Wn1T, Wn2T, Wm1T, Wm2T,
                                        sums, cnt, edat);

  node_pre_kernel<<<NN / 16, 256, 0, stream>>>(h, g1, bt1, We1T, be1, hn16, PQ);

  count_kernel<<<EE / 256, 256, 0, stream>>>(ei, cnt);
  scan_kernel<<<1, 1024, 0, stream>>>(cnt, cursor);
  scatter_kernel<<<EE / 256, 256, 0, stream>>>(ei, x, cursor, edat);

  edge_mlp_kernel<<<EBLOCKS, 256, 0, stream>>>(edat, PQ, We1 + 256 * 256,
                                               We2T, be2, sums);

  node_fused_kernel<<<NN / 16, 256, 0, stream>>>(h, hn16, sums, cnt,
                                                 Wn1T, bn1, Wn2T, bn2,
                                                 g2, bt2, Wm1T, bm1, Wm2T, bm2, out);
}